// Round 2
// baseline (1503.428 us; speedup 1.0000x reference)
//
#include <hip/hip_runtime.h>
#include <stdint.h>

#define NROWS 16384
#define DIM   128
#define VOCAB 8192
#define BN 64
#define BV 64
#define VSPLITS 4
#define SPLITV (VOCAB / VSPLITS)   /* 2048 */
#define NTILES (SPLITV / BV)       /* 32 */
#define MARGIN  1.5f
#define EMB_ELEMS (NROWS * DIM)    /* 2097152 */
#define LIST_CAP_MAX 4194304u

typedef __attribute__((ext_vector_type(8))) short bf16x8;
typedef __attribute__((ext_vector_type(4))) float f32x4;

__device__ __forceinline__ unsigned short f2bf(float f) {
  union { float f; unsigned u; } v; v.f = f;
  unsigned r = v.u + 0x7fffu + ((v.u >> 16) & 1u);
  return (unsigned short)(r >> 16);
}

__device__ __forceinline__ bf16x8 pack8(float4 a, float4 b) {
  bf16x8 r;
  r[0] = (short)f2bf(a.x); r[1] = (short)f2bf(a.y);
  r[2] = (short)f2bf(a.z); r[3] = (short)f2bf(a.w);
  r[4] = (short)f2bf(b.x); r[5] = (short)f2bf(b.y);
  r[6] = (short)f2bf(b.z); r[7] = (short)f2bf(b.w);
  return r;
}

// ---------------- prep: c2 = ||c||^2 (fp32), cbf = bf16(codebook) ----------------
__global__ __launch_bounds__(256) void k_prep(const float* __restrict__ cb,
                                              float* __restrict__ c2,
                                              unsigned short* __restrict__ cbf) {
  int tid = threadIdx.x;
  int r = blockIdx.x * 16 + (tid >> 4);
  int l = tid & 15;
  const float* rp = cb + (size_t)r * DIM + l * 8;
  float4 a = *(const float4*)rp;
  float4 b = *(const float4*)(rp + 4);
  float s = a.x*a.x + a.y*a.y + a.z*a.z + a.w*a.w
          + b.x*b.x + b.y*b.y + b.z*b.z + b.w*b.w;
  bf16x8 v8 = pack8(a, b);
  *(bf16x8*)(cbf + (size_t)r * DIM + l * 8) = v8;
#pragma unroll
  for (int o = 1; o < 16; o <<= 1) s += __shfl_xor(s, o);
  if (l == 0) c2[r] = s;
}

// ---------------- main fused kernel ----------------
__global__ __launch_bounds__(256) void k_main(
    const float* __restrict__ x, const float* __restrict__ c2g,
    const unsigned short* __restrict__ cbf,
    float* __restrict__ accum,                  // [NROWS][129] (num | s)
    unsigned long long* __restrict__ kApprox,   // [NROWS]
    unsigned int* __restrict__ cnt,
    unsigned int* __restrict__ list, unsigned int cap) {
  __shared__ unsigned short tile1[BV][136];   // codebook tile, row-major [v][d]
  __shared__ unsigned short tileT[144][72];   // transposed [d][v] + ones rows 128..143
  __shared__ unsigned short wlds[BN][72];     // weights tile [m][v]
  __shared__ float x2lds[BN];

  const int tid = threadIdx.x;
  const int lane = tid & 63;
  const int w = tid >> 6;               // wave 0..3
  const int wr = w >> 1, wc = w & 1;    // 2x2 wave grid for S
  const int l15 = lane & 15, lq = lane >> 4;
  const int blockRow = blockIdx.x * BN;
  const int vy = blockIdx.y;

  // preload x A-fragments (bf16) and row norms
  bf16x8 afrag[2][4];
  float x2p[2] = {0.f, 0.f};
#pragma unroll
  for (int mi = 0; mi < 2; ++mi) {
    int gr = blockRow + wr * 32 + mi * 16 + l15;
    const float* xr = x + (size_t)gr * DIM + lq * 8;
#pragma unroll
    for (int kf = 0; kf < 4; ++kf) {
      float4 a = *(const float4*)(xr + kf * 32);
      float4 b = *(const float4*)(xr + kf * 32 + 4);
      x2p[mi] += a.x*a.x + a.y*a.y + a.z*a.z + a.w*a.w
               + b.x*b.x + b.y*b.y + b.z*b.z + b.w*b.w;
      afrag[mi][kf] = pack8(a, b);
    }
    x2p[mi] += __shfl_xor(x2p[mi], 16);
    x2p[mi] += __shfl_xor(x2p[mi], 32);
  }
  if (lq == 0) {
    x2lds[wr * 32 + l15] = x2p[0];
    x2lds[wr * 32 + 16 + l15] = x2p[1];
  }
  // ones rows of tileT (col 128 of extended codebook = 1.0, 129..143 = 0)
  for (int idx = tid; idx < 16 * 72; idx += 256) {
    int d = 128 + idx / 72, v = idx % 72;
    tileT[d][v] = (d == 128) ? (unsigned short)0x3F80 : (unsigned short)0;
  }
  __syncthreads();
  float x2r[2][4];
#pragma unroll
  for (int mi = 0; mi < 2; ++mi)
#pragma unroll
    for (int j = 0; j < 4; ++j)
      x2r[mi][j] = x2lds[wr * 32 + mi * 16 + lq * 4 + j];

  f32x4 eacc[9];
#pragma unroll
  for (int db = 0; db < 9; ++db) eacc[db] = (f32x4){0.f, 0.f, 0.f, 0.f};
  float runmin[2][4];
#pragma unroll
  for (int mi = 0; mi < 2; ++mi)
#pragma unroll
    for (int j = 0; j < 4; ++j) runmin[mi][j] = 3.0e38f;

  const int stg_row = tid >> 2;   // 0..63
  const int stg_q = tid & 3;      // 0..3

  for (int it = 0; it < NTILES; ++it) {
    int vbase = vy * SPLITV + it * BV;
    __syncthreads();   // previous E-phase done reading tileT/wlds
    // ---- stage codebook tile (bf16): tile1 row-major + tileT transposed ----
    {
      union { uint4 u4[4]; unsigned short s[32]; } stg;
      const uint4* gsrc = (const uint4*)(cbf + (size_t)(vbase + stg_row) * DIM + stg_q * 32);
      stg.u4[0] = gsrc[0]; stg.u4[1] = gsrc[1];
      stg.u4[2] = gsrc[2]; stg.u4[3] = gsrc[3];
      uint4* t1 = (uint4*)&tile1[stg_row][stg_q * 32];
      t1[0] = stg.u4[0]; t1[1] = stg.u4[1]; t1[2] = stg.u4[2]; t1[3] = stg.u4[3];
      // transposed with q-XOR swizzle on the v byte-offset (kills 4-way write conflict)
      char* tb2 = ((char*)&tileT[0][0]) + (stg_q * 32) * 144 + ((stg_row * 2) ^ (stg_q << 5));
#pragma unroll
      for (int j = 0; j < 32; ++j)
        *(unsigned short*)(tb2 + j * 144) = stg.s[j];
    }
    __syncthreads();
    // ---- MFMA 1: S = X * C^T  (wave tile 32x32) ----
    f32x4 sacc[2][2];
#pragma unroll
    for (int mi = 0; mi < 2; ++mi)
#pragma unroll
      for (int ni = 0; ni < 2; ++ni) sacc[mi][ni] = (f32x4){0.f, 0.f, 0.f, 0.f};
#pragma unroll
    for (int kf = 0; kf < 4; ++kf) {
      bf16x8 b0 = *(const bf16x8*)&tile1[wc * 32 + l15][kf * 32 + lq * 8];
      bf16x8 b1 = *(const bf16x8*)&tile1[wc * 32 + 16 + l15][kf * 32 + lq * 8];
      sacc[0][0] = __builtin_amdgcn_mfma_f32_16x16x32_bf16(afrag[0][kf], b0, sacc[0][0], 0, 0, 0);
      sacc[0][1] = __builtin_amdgcn_mfma_f32_16x16x32_bf16(afrag[0][kf], b1, sacc[0][1], 0, 0, 0);
      sacc[1][0] = __builtin_amdgcn_mfma_f32_16x16x32_bf16(afrag[1][kf], b0, sacc[1][0], 0, 0, 0);
      sacc[1][1] = __builtin_amdgcn_mfma_f32_16x16x32_bf16(afrag[1][kf], b1, sacc[1][1], 0, 0, 0);
    }
    // ---- d2 / weights / argmin candidates ----
    float c2v[2];
    c2v[0] = c2g[vbase + wc * 32 + l15];
    c2v[1] = c2g[vbase + wc * 32 + 16 + l15];
#pragma unroll
    for (int mi = 0; mi < 2; ++mi) {
      float d2a[2][4];
#pragma unroll
      for (int ni = 0; ni < 2; ++ni)
#pragma unroll
        for (int j = 0; j < 4; ++j) {
          float d2 = fmaxf(fmaf(-2.f, sacc[mi][ni][j], x2r[mi][j] + c2v[ni]), 0.f);
          d2a[ni][j] = d2;
          float dist = sqrtf(d2) + 1e-8f;
          wlds[wr * 32 + mi * 16 + lq * 4 + j][wc * 32 + ni * 16 + l15] = f2bf(dist);
        }
#pragma unroll
      for (int j = 0; j < 4; ++j) {
        int grow = blockRow + wr * 32 + mi * 16 + lq * 4 + j;
        // 1) per-row min over this tile (both ni halves, 16 cols each)
        float rm = fminf(d2a[0][j], d2a[1][j]);
        rm = fminf(rm, __shfl_xor(rm, 1));
        rm = fminf(rm, __shfl_xor(rm, 2));
        rm = fminf(rm, __shfl_xor(rm, 4));
        rm = fminf(rm, __shfl_xor(rm, 8));
        // 2) update local + global running min FIRST
        if (rm < runmin[mi][j]) {
          runmin[mi][j] = rm;
          if (l15 == 0)
            atomicMin(&kApprox[grow], ((unsigned long long)__float_as_uint(rm) << 32));
        }
        // 3) tighten with cross-block global min (NaN-safe: fminf ignores NaN)
        float g = __uint_as_float((unsigned)(kApprox[grow] >> 32));
        float thr = fminf(runmin[mi][j], g) + MARGIN;
        // 4) emit candidates within margin of best-so-far
#pragma unroll
        for (int ni = 0; ni < 2; ++ni) {
          if (d2a[ni][j] <= thr) {
            unsigned pos = atomicAdd(cnt, 1u);
            if (pos < cap) {
              unsigned gv = (unsigned)(vbase + wc * 32 + ni * 16 + l15);
              list[pos] = ((unsigned)grow << 13) | gv;
            }
          }
        }
      }
    }
    __syncthreads();
    // ---- MFMA 2: E += W * [C | 1]  (wave owns 16 rows x 144 cols) ----
#pragma unroll
    for (int kk = 0; kk < 2; ++kk) {
      bf16x8 awf = *(const bf16x8*)&wlds[w * 16 + l15][kk * 32 + lq * 8];
#pragma unroll
      for (int db = 0; db < 9; ++db) {
        int d = db * 16 + l15;
        int q2 = (d >> 5) & 3;
        const char* tb = (const char*)&tileT[0][0];
        bf16x8 bw = *(const bf16x8*)(tb + d * 144 + (((kk * 32 + lq * 8) * 2) ^ (q2 << 5)));
        eacc[db] = __builtin_amdgcn_mfma_f32_16x16x32_bf16(awf, bw, eacc[db], 0, 0, 0);
      }
    }
  }
  // ---- flush embed partials ----
#pragma unroll
  for (int db = 0; db < 9; ++db) {
    int d = db * 16 + l15;
    if (d > 128) continue;
#pragma unroll
    for (int j = 0; j < 4; ++j) {
      int grow = blockRow + w * 16 + lq * 4 + j;
      atomicAdd(&accum[(size_t)grow * 129 + d], eacc[db][j]);
    }
  }
}

// ---------------- exact argmin fixup (fp64, one wave per candidate) ----------------
__global__ __launch_bounds__(256) void k_fix(const float* __restrict__ x,
                                             const float* __restrict__ cb,
                                             const unsigned int* __restrict__ list,
                                             const unsigned int* __restrict__ cnt,
                                             unsigned int cap,
                                             unsigned long long* __restrict__ kExact) {
  unsigned n = *cnt; if (n > cap) n = cap;
  int lane = threadIdx.x & 63;
  unsigned wave = blockIdx.x * (blockDim.x >> 6) + (threadIdx.x >> 6);
  unsigned nw = gridDim.x * (blockDim.x >> 6);
  for (unsigned e = wave; e < n; e += nw) {
    unsigned ent = list[e];
    unsigned row = ent >> 13;
    unsigned v = ent & 0x1FFFu;
    const float* xr = x + (size_t)row * DIM;
    const float* cr = cb + (size_t)v * DIM;
    float2 xa = *(const float2*)(xr + lane * 2);
    float2 ca = *(const float2*)(cr + lane * 2);
    double d0 = (double)xa.x - (double)ca.x;
    double d1 = (double)xa.y - (double)ca.y;
    double acc = d0 * d0 + d1 * d1;
    for (int off = 32; off; off >>= 1) acc += __shfl_down(acc, off);
    if (lane == 0)
      atomicMin(&kExact[row],
                ((unsigned long long)__float_as_uint((float)acc) << 32) | (unsigned long long)v);
  }
}

// ---------------- overflow rescue: full exact scan, one wave per row ----------------
__global__ __launch_bounds__(256) void k_rescue(const float* __restrict__ x,
                                                const float* __restrict__ cb,
                                                const unsigned int* __restrict__ cnt,
                                                unsigned int cap,
                                                unsigned long long* __restrict__ kExact) {
  if (*cnt <= cap) return;   // uniform early-out: rescue only needed on list overflow
  __shared__ float xs[4][128];
  int lane = threadIdx.x & 63;
  int wv = threadIdx.x >> 6;
  int row = blockIdx.x * 4 + wv;
  float2 xa = *(const float2*)(x + (size_t)row * DIM + lane * 2);
  xs[wv][lane * 2] = xa.x;
  xs[wv][lane * 2 + 1] = xa.y;
  __syncthreads();
  unsigned long long best = ~0ull;
  for (int v0 = 0; v0 < VOCAB; v0 += 64) {
    int v = v0 + lane;
    const float* cr = cb + (size_t)v * DIM;
    double acc = 0.0;
    for (int d = 0; d < DIM; ++d) {
      double diff = (double)xs[wv][d] - (double)cr[d];
      acc = fma(diff, diff, acc);
    }
    unsigned long long p = ((unsigned long long)__float_as_uint((float)acc) << 32)
                         | (unsigned long long)(unsigned)v;
    best = (p < best) ? p : best;
  }
#pragma unroll
  for (int off = 32; off; off >>= 1) {
    unsigned long long o = __shfl_xor(best, off);
    best = (o < best) ? o : best;
  }
  if (lane == 0) atomicMin(&kExact[row], best);
}

// ---------------- finalize ----------------
__global__ __launch_bounds__(256) void k_emb(const float* __restrict__ accum,
                                             float* __restrict__ out) {
  int i = blockIdx.x * 256 + threadIdx.x;
  int row = i >> 7, d = i & 127;
  float s = accum[(size_t)row * 129 + 128];
  out[i] = accum[(size_t)row * 129 + d] / s;
}

__global__ __launch_bounds__(256) void k_idx(const unsigned long long* __restrict__ kExact,
                                             float* __restrict__ out) {
  int n = blockIdx.x * 256 + threadIdx.x;
  out[EMB_ELEMS + n] = (float)(unsigned)(kExact[n] & 0x1FFFu);
}

extern "C" void kernel_launch(void* const* d_in, const int* in_sizes, int n_in,
                              void* d_out, int out_size, void* d_ws, size_t ws_size,
                              hipStream_t stream) {
  const float* x = (const float*)d_in[0];
  const float* cb = (const float*)d_in[1];
  float* out = (float*)d_out;

  char* ws = (char*)d_ws;
  size_t off = 0;
  float* accum = (float*)(ws + off); off += (size_t)NROWS * 129 * 4;
  float* c2 = (float*)(ws + off); off += (size_t)VOCAB * 4;
  unsigned short* cbf = (unsigned short*)(ws + off); off += (size_t)VOCAB * DIM * 2;
  unsigned long long* kApprox = (unsigned long long*)(ws + off); off += (size_t)NROWS * 8;
  unsigned long long* kExact = (unsigned long long*)(ws + off); off += (size_t)NROWS * 8;
  unsigned int* cnt = (unsigned int*)(ws + off); off += 64;
  unsigned int* list = (unsigned int*)(ws + off);
  size_t cap32 = (ws_size > off) ? (ws_size - off) / 4 : 0;
  unsigned cap = (unsigned)(cap32 > LIST_CAP_MAX ? LIST_CAP_MAX : cap32);

  hipMemsetAsync(accum, 0, (size_t)NROWS * 129 * 4, stream);
  hipMemsetAsync(kApprox, 0xFF, (size_t)NROWS * 8 * 2, stream);  // kApprox + kExact
  hipMemsetAsync(cnt, 0, 64, stream);

  k_prep<<<VOCAB / 16, 256, 0, stream>>>(cb, c2, cbf);
  k_main<<<dim3(NROWS / BN, VSPLITS), 256, 0, stream>>>(x, c2, cbf, accum, kApprox, cnt, list, cap);
  k_fix<<<1024, 256, 0, stream>>>(x, cb, list, cnt, cap, kExact);
  k_rescue<<<NROWS / 4, 256, 0, stream>>>(x, cb, cnt, cap, kExact);
  k_emb<<<EMB_ELEMS / 256, 256, 0, stream>>>(accum, out);
  k_idx<<<NROWS / 256, 256, 0, stream>>>(kExact, out);
}

// Round 3
// 782.124 us; speedup vs baseline: 1.9222x; 1.9222x over previous
//
#include <hip/hip_runtime.h>
#include <stdint.h>

#define NROWS 16384
#define DIM   128
#define VOCAB 8192
#define BN 64
#define BV 64
#define VSPLITS 4
#define SPLITV (VOCAB / VSPLITS)   /* 2048 */
#define NTILES (SPLITV / BV)       /* 32 */
#define MARGIN  0.8f
#define EMB_ELEMS (NROWS * DIM)    /* 2097152 */
#define LIST_CAP_MAX 4194304u
#define LCAP 1536

typedef __attribute__((ext_vector_type(8))) short bf16x8;
typedef __attribute__((ext_vector_type(4))) float f32x4;

__device__ __forceinline__ unsigned short f2bf(float f) {
  union { float f; unsigned u; } v; v.f = f;
  unsigned r = v.u + 0x7fffu + ((v.u >> 16) & 1u);
  return (unsigned short)(r >> 16);
}

__device__ __forceinline__ bf16x8 pack8(float4 a, float4 b) {
  bf16x8 r;
  r[0] = (short)f2bf(a.x); r[1] = (short)f2bf(a.y);
  r[2] = (short)f2bf(a.z); r[3] = (short)f2bf(a.w);
  r[4] = (short)f2bf(b.x); r[5] = (short)f2bf(b.y);
  r[6] = (short)f2bf(b.z); r[7] = (short)f2bf(b.w);
  return r;
}

// ---------------- prep: c2 = ||c||^2 (fp32), cbf = bf16(codebook) ----------------
__global__ __launch_bounds__(256) void k_prep(const float* __restrict__ cb,
                                              float* __restrict__ c2,
                                              unsigned short* __restrict__ cbf) {
  int tid = threadIdx.x;
  int r = blockIdx.x * 16 + (tid >> 4);
  int l = tid & 15;
  const float* rp = cb + (size_t)r * DIM + l * 8;
  float4 a = *(const float4*)rp;
  float4 b = *(const float4*)(rp + 4);
  float s = a.x*a.x + a.y*a.y + a.z*a.z + a.w*a.w
          + b.x*b.x + b.y*b.y + b.z*b.z + b.w*b.w;
  bf16x8 v8 = pack8(a, b);
  *(bf16x8*)(cbf + (size_t)r * DIM + l * 8) = v8;
#pragma unroll
  for (int o = 1; o < 16; o <<= 1) s += __shfl_xor(s, o);
  if (l == 0) c2[r] = s;
}

// ---------------- main fused kernel ----------------
__global__ __launch_bounds__(256) void k_main(
    const float* __restrict__ x, const float* __restrict__ c2g,
    const unsigned short* __restrict__ cbf,
    float* __restrict__ accum,                  // [NROWS][129] (num | s)
    unsigned long long* __restrict__ kApprox,   // [NROWS]
    unsigned int* __restrict__ cnt,
    unsigned int* __restrict__ list, unsigned int cap) {
  __shared__ unsigned short tile1[BV][136];   // codebook tile, row-major [v][d]
  __shared__ unsigned short tileT[144][72];   // transposed [d][v] + ones rows 128..143
  __shared__ unsigned short wlds[BN][72];     // weights tile [m][v]
  __shared__ float x2lds[BN];
  __shared__ unsigned int lbuf[LCAP];
  __shared__ unsigned int lcnt;
  __shared__ unsigned int gbase;

  const int tid = threadIdx.x;
  const int lane = tid & 63;
  const int w = tid >> 6;               // wave 0..3
  const int wr = w >> 1, wc = w & 1;    // 2x2 wave grid for S
  const int l15 = lane & 15, lq = lane >> 4;
  const int blockRow = blockIdx.x * BN;
  const int vy = blockIdx.y;

  if (tid == 0) lcnt = 0;

  // preload x A-fragments (bf16) and row norms
  bf16x8 afrag[2][4];
  float x2p[2] = {0.f, 0.f};
#pragma unroll
  for (int mi = 0; mi < 2; ++mi) {
    int gr = blockRow + wr * 32 + mi * 16 + l15;
    const float* xr = x + (size_t)gr * DIM + lq * 8;
#pragma unroll
    for (int kf = 0; kf < 4; ++kf) {
      float4 a = *(const float4*)(xr + kf * 32);
      float4 b = *(const float4*)(xr + kf * 32 + 4);
      x2p[mi] += a.x*a.x + a.y*a.y + a.z*a.z + a.w*a.w
               + b.x*b.x + b.y*b.y + b.z*b.z + b.w*b.w;
      afrag[mi][kf] = pack8(a, b);
    }
    x2p[mi] += __shfl_xor(x2p[mi], 16);
    x2p[mi] += __shfl_xor(x2p[mi], 32);
  }
  if (lq == 0) {
    x2lds[wr * 32 + l15] = x2p[0];
    x2lds[wr * 32 + 16 + l15] = x2p[1];
  }
  // ones rows of tileT (col 128 of extended codebook = 1.0, 129..143 = 0)
  for (int idx = tid; idx < 16 * 72; idx += 256) {
    int d = 128 + idx / 72, v = idx % 72;
    tileT[d][v] = (d == 128) ? (unsigned short)0x3F80 : (unsigned short)0;
  }
  __syncthreads();
  float x2r[2][4];
#pragma unroll
  for (int mi = 0; mi < 2; ++mi)
#pragma unroll
    for (int j = 0; j < 4; ++j)
      x2r[mi][j] = x2lds[wr * 32 + mi * 16 + lq * 4 + j];

  f32x4 eacc[9];
#pragma unroll
  for (int db = 0; db < 9; ++db) eacc[db] = (f32x4){0.f, 0.f, 0.f, 0.f};
  float runmin[2][4];
#pragma unroll
  for (int mi = 0; mi < 2; ++mi)
#pragma unroll
    for (int j = 0; j < 4; ++j) runmin[mi][j] = 3.0e38f;

  const int stg_row = tid >> 2;   // 0..63
  const int stg_q = tid & 3;      // 0..3

  for (int it = 0; it < NTILES; ++it) {
    int vbase = vy * SPLITV + it * BV;
    __syncthreads();   // previous E-phase done reading tileT/wlds
    // ---- stage codebook tile (bf16): tile1 row-major + tileT transposed ----
    {
      union { uint4 u4[4]; unsigned short s[32]; } stg;
      const uint4* gsrc = (const uint4*)(cbf + (size_t)(vbase + stg_row) * DIM + stg_q * 32);
      stg.u4[0] = gsrc[0]; stg.u4[1] = gsrc[1];
      stg.u4[2] = gsrc[2]; stg.u4[3] = gsrc[3];
      uint4* t1 = (uint4*)&tile1[stg_row][stg_q * 32];
      t1[0] = stg.u4[0]; t1[1] = stg.u4[1]; t1[2] = stg.u4[2]; t1[3] = stg.u4[3];
      // transposed with q-XOR swizzle on the v byte-offset (kills 4-way write conflict)
      char* tb2 = ((char*)&tileT[0][0]) + (stg_q * 32) * 144 + ((stg_row * 2) ^ (stg_q << 5));
#pragma unroll
      for (int j = 0; j < 32; ++j)
        *(unsigned short*)(tb2 + j * 144) = stg.s[j];
    }
    __syncthreads();
    // ---- MFMA 1: S = X * C^T  (wave tile 32x32) ----
    f32x4 sacc[2][2];
#pragma unroll
    for (int mi = 0; mi < 2; ++mi)
#pragma unroll
      for (int ni = 0; ni < 2; ++ni) sacc[mi][ni] = (f32x4){0.f, 0.f, 0.f, 0.f};
#pragma unroll
    for (int kf = 0; kf < 4; ++kf) {
      bf16x8 b0 = *(const bf16x8*)&tile1[wc * 32 + l15][kf * 32 + lq * 8];
      bf16x8 b1 = *(const bf16x8*)&tile1[wc * 32 + 16 + l15][kf * 32 + lq * 8];
      sacc[0][0] = __builtin_amdgcn_mfma_f32_16x16x32_bf16(afrag[0][kf], b0, sacc[0][0], 0, 0, 0);
      sacc[0][1] = __builtin_amdgcn_mfma_f32_16x16x32_bf16(afrag[0][kf], b1, sacc[0][1], 0, 0, 0);
      sacc[1][0] = __builtin_amdgcn_mfma_f32_16x16x32_bf16(afrag[1][kf], b0, sacc[1][0], 0, 0, 0);
      sacc[1][1] = __builtin_amdgcn_mfma_f32_16x16x32_bf16(afrag[1][kf], b1, sacc[1][1], 0, 0, 0);
    }
    // ---- d2 / weights / argmin candidates ----
    float c2v[2];
    c2v[0] = c2g[vbase + wc * 32 + l15];
    c2v[1] = c2g[vbase + wc * 32 + 16 + l15];
#pragma unroll
    for (int mi = 0; mi < 2; ++mi) {
      float d2a[2][4];
#pragma unroll
      for (int ni = 0; ni < 2; ++ni)
#pragma unroll
        for (int j = 0; j < 4; ++j) {
          float d2 = fmaxf(fmaf(-2.f, sacc[mi][ni][j], x2r[mi][j] + c2v[ni]), 0.f);
          d2a[ni][j] = d2;
          float dist = sqrtf(d2) + 1e-8f;
          wlds[wr * 32 + mi * 16 + lq * 4 + j][wc * 32 + ni * 16 + l15] = f2bf(dist);
        }
#pragma unroll
      for (int j = 0; j < 4; ++j) {
        int grow = blockRow + wr * 32 + mi * 16 + lq * 4 + j;
        // 1) per-row min over this tile (both ni halves, 16 cols each)
        float rm = fminf(d2a[0][j], d2a[1][j]);
        rm = fminf(rm, __shfl_xor(rm, 1));
        rm = fminf(rm, __shfl_xor(rm, 2));
        rm = fminf(rm, __shfl_xor(rm, 4));
        rm = fminf(rm, __shfl_xor(rm, 8));
        // 2) update local + global running min FIRST
        if (rm < runmin[mi][j]) {
          runmin[mi][j] = rm;
          if (l15 == 0)
            atomicMin(&kApprox[grow], ((unsigned long long)__float_as_uint(rm) << 32));
        }
        // 3) tighten with cross-block global min (stale read is safe: monotone min)
        float g = __uint_as_float((unsigned)(kApprox[grow] >> 32));
        float thr = fminf(runmin[mi][j], g) + MARGIN;
        // 4) emit candidates into the per-block LDS buffer
#pragma unroll
        for (int ni = 0; ni < 2; ++ni) {
          if (d2a[ni][j] <= thr) {
            unsigned gv = (unsigned)(vbase + wc * 32 + ni * 16 + l15);
            unsigned ent = ((unsigned)grow << 13) | gv;
            unsigned pos = atomicAdd(&lcnt, 1u);
            if (pos < LCAP) {
              lbuf[pos] = ent;
            } else {           // rare overflow: direct global emission
              unsigned gp = atomicAdd(cnt, 1u);
              if (gp < cap) list[gp] = ent;
            }
          }
        }
      }
    }
    __syncthreads();
    // ---- MFMA 2: E += W * [C | 1]  (wave owns 16 rows x 144 cols) ----
#pragma unroll
    for (int kk = 0; kk < 2; ++kk) {
      bf16x8 awf = *(const bf16x8*)&wlds[w * 16 + l15][kk * 32 + lq * 8];
#pragma unroll
      for (int db = 0; db < 9; ++db) {
        int d = db * 16 + l15;
        int q2 = (d >> 5) & 3;
        const char* tb = (const char*)&tileT[0][0];
        bf16x8 bw = *(const bf16x8*)(tb + d * 144 + (((kk * 32 + lq * 8) * 2) ^ (q2 << 5)));
        eacc[db] = __builtin_amdgcn_mfma_f32_16x16x32_bf16(awf, bw, eacc[db], 0, 0, 0);
      }
    }
  }
  // ---- flush candidate list: ONE global atomic per block ----
  __syncthreads();
  unsigned total = lcnt < LCAP ? lcnt : LCAP;
  if (tid == 0) gbase = atomicAdd(cnt, total);
  __syncthreads();
  for (unsigned i = tid; i < total; i += 256) {
    unsigned p = gbase + i;
    if (p < cap) list[p] = lbuf[i];
  }
  // ---- flush embed partials ----
#pragma unroll
  for (int db = 0; db < 9; ++db) {
    int d = db * 16 + l15;
    if (d > 128) continue;
#pragma unroll
    for (int j = 0; j < 4; ++j) {
      int grow = blockRow + w * 16 + lq * 4 + j;
      atomicAdd(&accum[(size_t)grow * 129 + d], eacc[db][j]);
    }
  }
}

// ---------------- exact argmin fixup (fp64, one wave per candidate) ----------------
__global__ __launch_bounds__(256) void k_fix(const float* __restrict__ x,
                                             const float* __restrict__ cb,
                                             const unsigned int* __restrict__ list,
                                             const unsigned int* __restrict__ cnt,
                                             unsigned int cap,
                                             unsigned long long* __restrict__ kExact) {
  unsigned n = *cnt; if (n > cap) n = cap;
  int lane = threadIdx.x & 63;
  unsigned wave = blockIdx.x * (blockDim.x >> 6) + (threadIdx.x >> 6);
  unsigned nw = gridDim.x * (blockDim.x >> 6);
  for (unsigned e = wave; e < n; e += nw) {
    unsigned ent = list[e];
    unsigned row = ent >> 13;
    unsigned v = ent & 0x1FFFu;
    const float* xr = x + (size_t)row * DIM;
    const float* cr = cb + (size_t)v * DIM;
    float2 xa = *(const float2*)(xr + lane * 2);
    float2 ca = *(const float2*)(cr + lane * 2);
    double d0 = (double)xa.x - (double)ca.x;
    double d1 = (double)xa.y - (double)ca.y;
    double acc = d0 * d0 + d1 * d1;
    for (int off = 32; off; off >>= 1) acc += __shfl_down(acc, off);
    if (lane == 0)
      atomicMin(&kExact[row],
                ((unsigned long long)__float_as_uint((float)acc) << 32) | (unsigned long long)v);
  }
}

// ---------------- overflow rescue: full exact scan, one wave per row ----------------
__global__ __launch_bounds__(256) void k_rescue(const float* __restrict__ x,
                                                const float* __restrict__ cb,
                                                const unsigned int* __restrict__ cnt,
                                                unsigned int cap,
                                                unsigned long long* __restrict__ kExact) {
  if (*cnt <= cap) return;   // uniform early-out: rescue only needed on list overflow
  __shared__ float xs[4][128];
  int lane = threadIdx.x & 63;
  int wv = threadIdx.x >> 6;
  int row = blockIdx.x * 4 + wv;
  float2 xa = *(const float2*)(x + (size_t)row * DIM + lane * 2);
  xs[wv][lane * 2] = xa.x;
  xs[wv][lane * 2 + 1] = xa.y;
  __syncthreads();
  unsigned long long best = ~0ull;
  for (int v0 = 0; v0 < VOCAB; v0 += 64) {
    int v = v0 + lane;
    const float* cr = cb + (size_t)v * DIM;
    double acc = 0.0;
    for (int d = 0; d < DIM; ++d) {
      double diff = (double)xs[wv][d] - (double)cr[d];
      acc = fma(diff, diff, acc);
    }
    unsigned long long p = ((unsigned long long)__float_as_uint((float)acc) << 32)
                         | (unsigned long long)(unsigned)v;
    best = (p < best) ? p : best;
  }
#pragma unroll
  for (int off = 32; off; off >>= 1) {
    unsigned long long o = __shfl_xor(best, off);
    best = (o < best) ? o : best;
  }
  if (lane == 0) atomicMin(&kExact[row], best);
}

// ---------------- finalize ----------------
__global__ __launch_bounds__(256) void k_emb(const float* __restrict__ accum,
                                             float* __restrict__ out) {
  int i = blockIdx.x * 256 + threadIdx.x;
  int row = i >> 7, d = i & 127;
  float s = accum[(size_t)row * 129 + 128];
  out[i] = accum[(size_t)row * 129 + d] / s;
}

__global__ __launch_bounds__(256) void k_idx(const unsigned long long* __restrict__ kExact,
                                             float* __restrict__ out) {
  int n = blockIdx.x * 256 + threadIdx.x;
  out[EMB_ELEMS + n] = (float)(unsigned)(kExact[n] & 0x1FFFu);
}

extern "C" void kernel_launch(void* const* d_in, const int* in_sizes, int n_in,
                              void* d_out, int out_size, void* d_ws, size_t ws_size,
                              hipStream_t stream) {
  const float* x = (const float*)d_in[0];
  const float* cb = (const float*)d_in[1];
  float* out = (float*)d_out;

  char* ws = (char*)d_ws;
  size_t off = 0;
  float* accum = (float*)(ws + off); off += (size_t)NROWS * 129 * 4;
  float* c2 = (float*)(ws + off); off += (size_t)VOCAB * 4;
  unsigned short* cbf = (unsigned short*)(ws + off); off += (size_t)VOCAB * DIM * 2;
  unsigned long long* kApprox = (unsigned long long*)(ws + off); off += (size_t)NROWS * 8;
  unsigned long long* kExact = (unsigned long long*)(ws + off); off += (size_t)NROWS * 8;
  unsigned int* cnt = (unsigned int*)(ws + off); off += 64;
  unsigned int* list = (unsigned int*)(ws + off);
  size_t cap32 = (ws_size > off) ? (ws_size - off) / 4 : 0;
  unsigned cap = (unsigned)(cap32 > LIST_CAP_MAX ? LIST_CAP_MAX : cap32);

  hipMemsetAsync(accum, 0, (size_t)NROWS * 129 * 4, stream);
  hipMemsetAsync(kApprox, 0xFF, (size_t)NROWS * 8 * 2, stream);  // kApprox + kExact
  hipMemsetAsync(cnt, 0, 64, stream);

  k_prep<<<VOCAB / 16, 256, 0, stream>>>(cb, c2, cbf);
  k_main<<<dim3(NROWS / BN, VSPLITS), 256, 0, stream>>>(x, c2, cbf, accum, kApprox, cnt, list, cap);
  k_fix<<<1024, 256, 0, stream>>>(x, cb, list, cnt, cap, kExact);
  k_rescue<<<NROWS / 4, 256, 0, stream>>>(x, cb, cnt, cap, kExact);
  k_emb<<<EMB_ELEMS / 256, 256, 0, stream>>>(accum, out);
  k_idx<<<NROWS / 256, 256, 0, stream>>>(kExact, out);
}

// Round 5
// 533.979 us; speedup vs baseline: 2.8155x; 1.4647x over previous
//
#include <hip/hip_runtime.h>
#include <stdint.h>

#define NROWS 16384
#define DIM   128
#define VOCAB 8192
#define BN 64
#define BV 64
#define VSPLITS 4
#define SPLITV (VOCAB / VSPLITS)   /* 2048 */
#define NTILES (SPLITV / BV)       /* 32 */
#define MARGIN  0.8f
#define EMB_ELEMS (NROWS * DIM)    /* 2097152 */
#define LIST_CAP_MAX 4194304u
#define LCAP 1536

typedef __attribute__((ext_vector_type(8))) short bf16x8;
typedef __attribute__((ext_vector_type(4))) float f32x4;

__device__ __forceinline__ unsigned short f2bf(float f) {
  union { float f; unsigned u; } v; v.f = f;
  unsigned r = v.u + 0x7fffu + ((v.u >> 16) & 1u);
  return (unsigned short)(r >> 16);
}

__device__ __forceinline__ bf16x8 pack8(float4 a, float4 b) {
  bf16x8 r;
  r[0] = (short)f2bf(a.x); r[1] = (short)f2bf(a.y);
  r[2] = (short)f2bf(a.z); r[3] = (short)f2bf(a.w);
  r[4] = (short)f2bf(b.x); r[5] = (short)f2bf(b.y);
  r[6] = (short)f2bf(b.z); r[7] = (short)f2bf(b.w);
  return r;
}

// ---------------- prep: c2 = ||c||^2 (fp32), cbf = bf16(codebook) ----------------
__global__ __launch_bounds__(256) void k_prep(const float* __restrict__ cb,
                                              float* __restrict__ c2,
                                              unsigned short* __restrict__ cbf) {
  int tid = threadIdx.x;
  int r = blockIdx.x * 16 + (tid >> 4);
  int l = tid & 15;
  const float* rp = cb + (size_t)r * DIM + l * 8;
  float4 a = *(const float4*)rp;
  float4 b = *(const float4*)(rp + 4);
  float s = a.x*a.x + a.y*a.y + a.z*a.z + a.w*a.w
          + b.x*b.x + b.y*b.y + b.z*b.z + b.w*b.w;
  bf16x8 v8 = pack8(a, b);
  *(bf16x8*)(cbf + (size_t)r * DIM + l * 8) = v8;
#pragma unroll
  for (int o = 1; o < 16; o <<= 1) s += __shfl_xor(s, o);
  if (l == 0) c2[r] = s;
}

// ---------------- main fused kernel ----------------
__global__ __launch_bounds__(256) void k_main(
    const float* __restrict__ x, const float* __restrict__ c2g,
    const unsigned short* __restrict__ cbf,
    float* __restrict__ accum,                  // [NROWS][129] (num | s)
    unsigned int* __restrict__ cnt,
    unsigned int* __restrict__ list, unsigned int cap) {
  __shared__ unsigned short tile1[BV][136];   // codebook tile, row-major [v][d]
  __shared__ unsigned short tileT[144][72];   // transposed [d][v] + ones rows 128..143
  __shared__ unsigned short wlds[BN][72];     // weights tile [m][v]
  __shared__ float x2lds[BN];
  __shared__ unsigned int lbuf[LCAP];
  __shared__ unsigned int lcnt;
  __shared__ unsigned int gbase;

  const int tid = threadIdx.x;
  const int lane = tid & 63;
  const int w = tid >> 6;               // wave 0..3
  const int wr = w >> 1, wc = w & 1;    // 2x2 wave grid for S
  const int l15 = lane & 15, lq = lane >> 4;
  const int blockRow = blockIdx.x * BN;
  const int vy = blockIdx.y;

  if (tid == 0) lcnt = 0;

  // preload x A-fragments (bf16) and row norms
  bf16x8 afrag[2][4];
  float x2p[2] = {0.f, 0.f};
#pragma unroll
  for (int mi = 0; mi < 2; ++mi) {
    int gr = blockRow + wr * 32 + mi * 16 + l15;
    const float* xr = x + (size_t)gr * DIM + lq * 8;
#pragma unroll
    for (int kf = 0; kf < 4; ++kf) {
      float4 a = *(const float4*)(xr + kf * 32);
      float4 b = *(const float4*)(xr + kf * 32 + 4);
      x2p[mi] += a.x*a.x + a.y*a.y + a.z*a.z + a.w*a.w
               + b.x*b.x + b.y*b.y + b.z*b.z + b.w*b.w;
      afrag[mi][kf] = pack8(a, b);
    }
    x2p[mi] += __shfl_xor(x2p[mi], 16);
    x2p[mi] += __shfl_xor(x2p[mi], 32);
  }
  if (lq == 0) {
    x2lds[wr * 32 + l15] = x2p[0];
    x2lds[wr * 32 + 16 + l15] = x2p[1];
  }
  // ones rows of tileT (col 128 of extended codebook = 1.0, 129..143 = 0)
  for (int idx = tid; idx < 16 * 72; idx += 256) {
    int d = 128 + idx / 72, v = idx % 72;
    tileT[d][v] = (d == 128) ? (unsigned short)0x3F80 : (unsigned short)0;
  }
  __syncthreads();
  float x2r[2][4];
#pragma unroll
  for (int mi = 0; mi < 2; ++mi)
#pragma unroll
    for (int j = 0; j < 4; ++j)
      x2r[mi][j] = x2lds[wr * 32 + mi * 16 + lq * 4 + j];

  f32x4 eacc[9];
#pragma unroll
  for (int db = 0; db < 9; ++db) eacc[db] = (f32x4){0.f, 0.f, 0.f, 0.f};
  float runmin[2][4];
#pragma unroll
  for (int mi = 0; mi < 2; ++mi)
#pragma unroll
    for (int j = 0; j < 4; ++j) runmin[mi][j] = 3.0e38f;

  const int stg_row = tid >> 2;   // 0..63
  const int stg_q = tid & 3;      // 0..3

  for (int it = 0; it < NTILES; ++it) {
    int vbase = vy * SPLITV + it * BV;
    __syncthreads();   // previous E-phase done reading tileT/wlds
    // ---- stage codebook tile (bf16): tile1 row-major + tileT transposed ----
    {
      union { uint4 u4[4]; unsigned short s[32]; } stg;
      const uint4* gsrc = (const uint4*)(cbf + (size_t)(vbase + stg_row) * DIM + stg_q * 32);
      stg.u4[0] = gsrc[0]; stg.u4[1] = gsrc[1];
      stg.u4[2] = gsrc[2]; stg.u4[3] = gsrc[3];
      uint4* t1 = (uint4*)&tile1[stg_row][stg_q * 32];
      t1[0] = stg.u4[0]; t1[1] = stg.u4[1]; t1[2] = stg.u4[2]; t1[3] = stg.u4[3];
      // transposed with q-XOR swizzle on the v byte-offset (kills 4-way write conflict)
      char* tb2 = ((char*)&tileT[0][0]) + (stg_q * 32) * 144 + ((stg_row * 2) ^ (stg_q << 5));
#pragma unroll
      for (int j = 0; j < 32; ++j)
        *(unsigned short*)(tb2 + j * 144) = stg.s[j];
    }
    __syncthreads();
    // ---- MFMA 1: S = X * C^T  (wave tile 32x32) ----
    f32x4 sacc[2][2];
#pragma unroll
    for (int mi = 0; mi < 2; ++mi)
#pragma unroll
      for (int ni = 0; ni < 2; ++ni) sacc[mi][ni] = (f32x4){0.f, 0.f, 0.f, 0.f};
#pragma unroll
    for (int kf = 0; kf < 4; ++kf) {
      bf16x8 b0 = *(const bf16x8*)&tile1[wc * 32 + l15][kf * 32 + lq * 8];
      bf16x8 b1 = *(const bf16x8*)&tile1[wc * 32 + 16 + l15][kf * 32 + lq * 8];
      sacc[0][0] = __builtin_amdgcn_mfma_f32_16x16x32_bf16(afrag[0][kf], b0, sacc[0][0], 0, 0, 0);
      sacc[0][1] = __builtin_amdgcn_mfma_f32_16x16x32_bf16(afrag[0][kf], b1, sacc[0][1], 0, 0, 0);
      sacc[1][0] = __builtin_amdgcn_mfma_f32_16x16x32_bf16(afrag[1][kf], b0, sacc[1][0], 0, 0, 0);
      sacc[1][1] = __builtin_amdgcn_mfma_f32_16x16x32_bf16(afrag[1][kf], b1, sacc[1][1], 0, 0, 0);
    }
    // ---- d2 / weights / argmin candidates ----
    float c2v[2];
    c2v[0] = c2g[vbase + wc * 32 + l15];
    c2v[1] = c2g[vbase + wc * 32 + 16 + l15];
#pragma unroll
    for (int mi = 0; mi < 2; ++mi) {
      float d2a[2][4];
#pragma unroll
      for (int ni = 0; ni < 2; ++ni)
#pragma unroll
        for (int j = 0; j < 4; ++j) {
          float d2 = fmaxf(fmaf(-2.f, sacc[mi][ni][j], x2r[mi][j] + c2v[ni]), 0.f);
          d2a[ni][j] = d2;
          float dist = sqrtf(d2) + 1e-8f;
          wlds[wr * 32 + mi * 16 + lq * 4 + j][wc * 32 + ni * 16 + l15] = f2bf(dist);
        }
#pragma unroll
      for (int j = 0; j < 4; ++j) {
        int grow = blockRow + wr * 32 + mi * 16 + lq * 4 + j;
        // 1) per-row min over this tile (both ni halves, 16 cols each)
        float rm = fminf(d2a[0][j], d2a[1][j]);
        rm = fminf(rm, __shfl_xor(rm, 1));
        rm = fminf(rm, __shfl_xor(rm, 2));
        rm = fminf(rm, __shfl_xor(rm, 4));
        rm = fminf(rm, __shfl_xor(rm, 8));
        // 2) update local running min (no global traffic in the loop)
        runmin[mi][j] = fminf(runmin[mi][j], rm);
        float thr = runmin[mi][j] + MARGIN;
        // 3) emit candidates into the per-block LDS buffer
#pragma unroll
        for (int ni = 0; ni < 2; ++ni) {
          if (d2a[ni][j] <= thr) {
            unsigned gv = (unsigned)(vbase + wc * 32 + ni * 16 + l15);
            unsigned ent = ((unsigned)grow << 13) | gv;
            unsigned pos = atomicAdd(&lcnt, 1u);
            if (pos < LCAP) {
              lbuf[pos] = ent;
            } else {           // rare overflow: direct global emission
              unsigned gp = atomicAdd(cnt, 1u);
              if (gp < cap) list[gp] = ent;
            }
          }
        }
      }
    }
    __syncthreads();
    // ---- MFMA 2: E += W * [C | 1]  (wave owns 16 rows x 144 cols) ----
#pragma unroll
    for (int kk = 0; kk < 2; ++kk) {
      bf16x8 awf = *(const bf16x8*)&wlds[w * 16 + l15][kk * 32 + lq * 8];
#pragma unroll
      for (int db = 0; db < 9; ++db) {
        int d = db * 16 + l15;
        int q2 = (d >> 5) & 3;
        const char* tb = (const char*)&tileT[0][0];
        bf16x8 bw = *(const bf16x8*)(tb + d * 144 + (((kk * 32 + lq * 8) * 2) ^ (q2 << 5)));
        eacc[db] = __builtin_amdgcn_mfma_f32_16x16x32_bf16(awf, bw, eacc[db], 0, 0, 0);
      }
    }
  }
  // ---- flush candidate list: ONE global atomic per block ----
  __syncthreads();
  unsigned total = lcnt < LCAP ? lcnt : LCAP;
  if (tid == 0) gbase = atomicAdd(cnt, total);
  __syncthreads();
  for (unsigned i = tid; i < total; i += 256) {
    unsigned p = gbase + i;
    if (p < cap) list[p] = lbuf[i];
  }
  // ---- flush embed partials ----
#pragma unroll
  for (int db = 0; db < 9; ++db) {
    int d = db * 16 + l15;
    if (d > 128) continue;
#pragma unroll
    for (int j = 0; j < 4; ++j) {
      int grow = blockRow + w * 16 + lq * 4 + j;
      atomicAdd(&accum[(size_t)grow * 129 + d], eacc[db][j]);
    }
  }
}

// ---------------- exact argmin fixup (fp64, one wave per candidate) ----------------
__global__ __launch_bounds__(256) void k_fix(const float* __restrict__ x,
                                             const float* __restrict__ cb,
                                             const unsigned int* __restrict__ list,
                                             const unsigned int* __restrict__ cnt,
                                             unsigned int cap,
                                             unsigned long long* __restrict__ kExact) {
  unsigned n = *cnt; if (n > cap) n = cap;
  int lane = threadIdx.x & 63;
  unsigned wave = blockIdx.x * (blockDim.x >> 6) + (threadIdx.x >> 6);
  unsigned nw = gridDim.x * (blockDim.x >> 6);
  for (unsigned e = wave; e < n; e += nw) {
    unsigned ent = list[e];
    unsigned row = ent >> 13;
    unsigned v = ent & 0x1FFFu;
    const float* xr = x + (size_t)row * DIM;
    const float* cr = cb + (size_t)v * DIM;
    float2 xa = *(const float2*)(xr + lane * 2);
    float2 ca = *(const float2*)(cr + lane * 2);
    double d0 = (double)xa.x - (double)ca.x;
    double d1 = (double)xa.y - (double)ca.y;
    double acc = d0 * d0 + d1 * d1;
    for (int off = 32; off; off >>= 1) acc += __shfl_down(acc, off);
    if (lane == 0)
      atomicMin(&kExact[row],
                ((unsigned long long)__float_as_uint((float)acc) << 32) | (unsigned long long)v);
  }
}

// ---------------- overflow rescue: full exact scan, one wave per row ----------------
__global__ __launch_bounds__(256) void k_rescue(const float* __restrict__ x,
                                                const float* __restrict__ cb,
                                                const unsigned int* __restrict__ cnt,
                                                unsigned int cap,
                                                unsigned long long* __restrict__ kExact) {
  if (*cnt <= cap) return;   // uniform early-out: rescue only needed on list overflow
  __shared__ float xs[4][128];
  int lane = threadIdx.x & 63;
  int wv = threadIdx.x >> 6;
  int row = blockIdx.x * 4 + wv;
  float2 xa = *(const float2*)(x + (size_t)row * DIM + lane * 2);
  xs[wv][lane * 2] = xa.x;
  xs[wv][lane * 2 + 1] = xa.y;
  __syncthreads();
  unsigned long long best = ~0ull;
  for (int v0 = 0; v0 < VOCAB; v0 += 64) {
    int v = v0 + lane;
    const float* cr = cb + (size_t)v * DIM;
    double acc = 0.0;
    for (int d = 0; d < DIM; ++d) {
      double diff = (double)xs[wv][d] - (double)cr[d];
      acc = fma(diff, diff, acc);
    }
    unsigned long long p = ((unsigned long long)__float_as_uint((float)acc) << 32)
                         | (unsigned long long)(unsigned)v;
    best = (p < best) ? p : best;
  }
#pragma unroll
  for (int off = 32; off; off >>= 1) {
    unsigned long long o = __shfl_xor(best, off);
    best = (o < best) ? o : best;
  }
  if (lane == 0) atomicMin(&kExact[row], best);
}

// ---------------- finalize ----------------
__global__ __launch_bounds__(256) void k_emb(const float* __restrict__ accum,
                                             float* __restrict__ out) {
  int i = blockIdx.x * 256 + threadIdx.x;
  int row = i >> 7, d = i & 127;
  float s = accum[(size_t)row * 129 + 128];
  out[i] = accum[(size_t)row * 129 + d] / s;
}

__global__ __launch_bounds__(256) void k_idx(const unsigned long long* __restrict__ kExact,
                                             float* __restrict__ out) {
  int n = blockIdx.x * 256 + threadIdx.x;
  out[EMB_ELEMS + n] = (float)(unsigned)(kExact[n] & 0x1FFFu);
}

extern "C" void kernel_launch(void* const* d_in, const int* in_sizes, int n_in,
                              void* d_out, int out_size, void* d_ws, size_t ws_size,
                              hipStream_t stream) {
  const float* x = (const float*)d_in[0];
  const float* cb = (const float*)d_in[1];
  float* out = (float*)d_out;

  char* ws = (char*)d_ws;
  size_t off = 0;
  float* accum = (float*)(ws + off); off += (size_t)NROWS * 129 * 4;
  float* c2 = (float*)(ws + off); off += (size_t)VOCAB * 4;
  unsigned short* cbf = (unsigned short*)(ws + off); off += (size_t)VOCAB * DIM * 2;
  unsigned long long* kExact = (unsigned long long*)(ws + off); off += (size_t)NROWS * 8;
  unsigned int* cnt = (unsigned int*)(ws + off); off += 64;
  unsigned int* list = (unsigned int*)(ws + off);
  size_t cap32 = (ws_size > off) ? (ws_size - off) / 4 : 0;
  unsigned cap = (unsigned)(cap32 > LIST_CAP_MAX ? LIST_CAP_MAX : cap32);

  hipMemsetAsync(accum, 0, (size_t)NROWS * 129 * 4, stream);
  hipMemsetAsync(kExact, 0xFF, (size_t)NROWS * 8, stream);
  hipMemsetAsync(cnt, 0, 64, stream);

  k_prep<<<VOCAB / 16, 256, 0, stream>>>(cb, c2, cbf);
  k_main<<<dim3(NROWS / BN, VSPLITS), 256, 0, stream>>>(x, c2, cbf, accum, cnt, list, cap);
  k_fix<<<1024, 256, 0, stream>>>(x, cb, list, cnt, cap, kExact);
  k_rescue<<<NROWS / 4, 256, 0, stream>>>(x, cb, cnt, cap, kExact);
  k_emb<<<EMB_ELEMS / 256, 256, 0, stream>>>(accum, out);
  k_idx<<<NROWS / 256, 256, 0, stream>>>(kExact, out);
}

// Round 6
// 524.527 us; speedup vs baseline: 2.8663x; 1.0180x over previous
//
#include <hip/hip_runtime.h>
#include <stdint.h>

#define NROWS 16384
#define DIM   128
#define VOCAB 8192
#define BN 64
#define BV 64
#define VSPLITS 4
#define SPLITV (VOCAB / VSPLITS)   /* 2048 */
#define NTILES (SPLITV / BV)       /* 32 */
#define MARGIN  0.8f
#define EMB_ELEMS (NROWS * DIM)    /* 2097152 */
#define LIST_CAP_MAX 4194304u
#define LCAP 1024

typedef __attribute__((ext_vector_type(8))) short bf16x8;
typedef __attribute__((ext_vector_type(4))) float f32x4;

__device__ __forceinline__ unsigned short f2bf(float f) {
  union { float f; unsigned u; } v; v.f = f;
  unsigned r = v.u + 0x7fffu + ((v.u >> 16) & 1u);
  return (unsigned short)(r >> 16);
}

__device__ __forceinline__ bf16x8 pack8(float4 a, float4 b) {
  bf16x8 r;
  r[0] = (short)f2bf(a.x); r[1] = (short)f2bf(a.y);
  r[2] = (short)f2bf(a.z); r[3] = (short)f2bf(a.w);
  r[4] = (short)f2bf(b.x); r[5] = (short)f2bf(b.y);
  r[6] = (short)f2bf(b.z); r[7] = (short)f2bf(b.w);
  return r;
}

// ---------------- prep: c2 = ||c||^2 (fp32), cbf = bf16(codebook) ----------------
__global__ __launch_bounds__(256) void k_prep(const float* __restrict__ cb,
                                              float* __restrict__ c2,
                                              unsigned short* __restrict__ cbf) {
  int tid = threadIdx.x;
  int r = blockIdx.x * 16 + (tid >> 4);
  int l = tid & 15;
  const float* rp = cb + (size_t)r * DIM + l * 8;
  float4 a = *(const float4*)rp;
  float4 b = *(const float4*)(rp + 4);
  float s = a.x*a.x + a.y*a.y + a.z*a.z + a.w*a.w
          + b.x*b.x + b.y*b.y + b.z*b.z + b.w*b.w;
  bf16x8 v8 = pack8(a, b);
  *(bf16x8*)(cbf + (size_t)r * DIM + l * 8) = v8;
#pragma unroll
  for (int o = 1; o < 16; o <<= 1) s += __shfl_xor(s, o);
  if (l == 0) c2[r] = s;
}

// ---------------- main fused kernel ----------------
__global__ __launch_bounds__(256) void k_main(
    const float* __restrict__ x, const float* __restrict__ c2g,
    const unsigned short* __restrict__ cbf,
    float* __restrict__ accum,                  // [NROWS][129] (num | s)
    unsigned int* __restrict__ cnt,
    unsigned int* __restrict__ list, unsigned int cap) {
  __shared__ unsigned short tile1[BV][136];   // codebook tile, row-major [v][d]
  __shared__ unsigned short tileT[144][72];   // transposed [d][v] + ones rows 128..143
  __shared__ unsigned short wlds[BN][72];     // weights tile [m][v]
  __shared__ float x2lds[BN];
  __shared__ unsigned int lbuf[LCAP];
  __shared__ unsigned int lcnt;
  __shared__ unsigned int gbase;

  const int tid = threadIdx.x;
  const int lane = tid & 63;
  const int w = tid >> 6;               // wave 0..3
  const int wr = w >> 1, wc = w & 1;    // 2x2 wave grid for S
  const int l15 = lane & 15, lq = lane >> 4;
  const int blockRow = blockIdx.x * BN;
  const int vy = blockIdx.y;

  if (tid == 0) lcnt = 0;

  // preload x A-fragments (bf16) and row norms
  bf16x8 afrag[2][4];
  float x2p[2] = {0.f, 0.f};
#pragma unroll
  for (int mi = 0; mi < 2; ++mi) {
    int gr = blockRow + wr * 32 + mi * 16 + l15;
    const float* xr = x + (size_t)gr * DIM + lq * 8;
#pragma unroll
    for (int kf = 0; kf < 4; ++kf) {
      float4 a = *(const float4*)(xr + kf * 32);
      float4 b = *(const float4*)(xr + kf * 32 + 4);
      x2p[mi] += a.x*a.x + a.y*a.y + a.z*a.z + a.w*a.w
               + b.x*b.x + b.y*b.y + b.z*b.z + b.w*b.w;
      afrag[mi][kf] = pack8(a, b);
    }
    x2p[mi] += __shfl_xor(x2p[mi], 16);
    x2p[mi] += __shfl_xor(x2p[mi], 32);
  }
  if (lq == 0) {
    x2lds[wr * 32 + l15] = x2p[0];
    x2lds[wr * 32 + 16 + l15] = x2p[1];
  }
  // ones rows of tileT (col 128 of extended codebook = 1.0, 129..143 = 0)
  // d=128 row: S(128)=0 (no swizzle); rows 136..143 are zero so swizzle-safe.
  for (int idx = tid; idx < 16 * 72; idx += 256) {
    int d = 128 + idx / 72, v = idx % 72;
    tileT[d][v] = (d == 128) ? (unsigned short)0x3F80 : (unsigned short)0;
  }
  __syncthreads();
  float x2r[2][4];
#pragma unroll
  for (int mi = 0; mi < 2; ++mi)
#pragma unroll
    for (int j = 0; j < 4; ++j)
      x2r[mi][j] = x2lds[wr * 32 + mi * 16 + lq * 4 + j];

  f32x4 eacc[9];
#pragma unroll
  for (int db = 0; db < 9; ++db) eacc[db] = (f32x4){0.f, 0.f, 0.f, 0.f};
  float runmin[2][4];
#pragma unroll
  for (int mi = 0; mi < 2; ++mi)
#pragma unroll
    for (int j = 0; j < 4; ++j) runmin[mi][j] = 3.0e38f;

  // staging assignment: 4 v-rows x 8 d per thread
  const int sv = (tid >> 4) * 4;    // 0..60
  const int sd = (tid & 15) * 8;    // 0..120
  const int sS = (tid & 7) << 4;    // S(d) = ((d>>3)&7)<<4, constant for this thread's 8 d's

  for (int it = 0; it < NTILES; ++it) {
    int vbase = vy * SPLITV + it * BV;
    __syncthreads();   // previous E-phase done reading tileT/wlds
    // ---- stage codebook tile (bf16): tile1 row-major + tileT transposed ----
    {
      uint4 r0 = *(const uint4*)(cbf + (size_t)(vbase + sv + 0) * DIM + sd);
      uint4 r1 = *(const uint4*)(cbf + (size_t)(vbase + sv + 1) * DIM + sd);
      uint4 r2 = *(const uint4*)(cbf + (size_t)(vbase + sv + 2) * DIM + sd);
      uint4 r3 = *(const uint4*)(cbf + (size_t)(vbase + sv + 3) * DIM + sd);
      *(uint4*)&tile1[sv + 0][sd] = r0;
      *(uint4*)&tile1[sv + 1][sd] = r1;
      *(uint4*)&tile1[sv + 2][sd] = r2;
      *(uint4*)&tile1[sv + 3][sd] = r3;
      const unsigned short* s0 = (const unsigned short*)&r0;
      const unsigned short* s1 = (const unsigned short*)&r1;
      const unsigned short* s2 = (const unsigned short*)&r2;
      const unsigned short* s3 = (const unsigned short*)&r3;
      char* tb = (char*)&tileT[0][0];
#pragma unroll
      for (int k = 0; k < 8; ++k) {
        uint2 val;
        val.x = (unsigned)s0[k] | ((unsigned)s1[k] << 16);
        val.y = (unsigned)s2[k] | ((unsigned)s3[k] << 16);
        *(uint2*)(tb + (sd + k) * 144 + ((sv * 2) ^ sS)) = val;
      }
    }
    __syncthreads();
    // ---- MFMA 1: S = X * C^T  (wave tile 32x32) ----
    f32x4 sacc[2][2];
#pragma unroll
    for (int mi = 0; mi < 2; ++mi)
#pragma unroll
      for (int ni = 0; ni < 2; ++ni) sacc[mi][ni] = (f32x4){0.f, 0.f, 0.f, 0.f};
#pragma unroll
    for (int kf = 0; kf < 4; ++kf) {
      bf16x8 b0 = *(const bf16x8*)&tile1[wc * 32 + l15][kf * 32 + lq * 8];
      bf16x8 b1 = *(const bf16x8*)&tile1[wc * 32 + 16 + l15][kf * 32 + lq * 8];
      sacc[0][0] = __builtin_amdgcn_mfma_f32_16x16x32_bf16(afrag[0][kf], b0, sacc[0][0], 0, 0, 0);
      sacc[0][1] = __builtin_amdgcn_mfma_f32_16x16x32_bf16(afrag[0][kf], b1, sacc[0][1], 0, 0, 0);
      sacc[1][0] = __builtin_amdgcn_mfma_f32_16x16x32_bf16(afrag[1][kf], b0, sacc[1][0], 0, 0, 0);
      sacc[1][1] = __builtin_amdgcn_mfma_f32_16x16x32_bf16(afrag[1][kf], b1, sacc[1][1], 0, 0, 0);
    }
    // ---- d2 / weights / argmin candidates ----
    float c2v[2];
    c2v[0] = c2g[vbase + wc * 32 + l15];
    c2v[1] = c2g[vbase + wc * 32 + 16 + l15];
#pragma unroll
    for (int mi = 0; mi < 2; ++mi) {
      float d2a[2][4];
#pragma unroll
      for (int ni = 0; ni < 2; ++ni)
#pragma unroll
        for (int j = 0; j < 4; ++j) {
          float d2 = fmaxf(fmaf(-2.f, sacc[mi][ni][j], x2r[mi][j] + c2v[ni]), 0.f);
          d2a[ni][j] = d2;
          float dist = sqrtf(d2) + 1e-8f;
          wlds[wr * 32 + mi * 16 + lq * 4 + j][wc * 32 + ni * 16 + l15] = f2bf(dist);
        }
#pragma unroll
      for (int j = 0; j < 4; ++j) {
        int grow = blockRow + wr * 32 + mi * 16 + lq * 4 + j;
        // 1) per-row min over this tile (both ni halves, 16 cols each)
        float rm = fminf(d2a[0][j], d2a[1][j]);
        rm = fminf(rm, __shfl_xor(rm, 1));
        rm = fminf(rm, __shfl_xor(rm, 2));
        rm = fminf(rm, __shfl_xor(rm, 4));
        rm = fminf(rm, __shfl_xor(rm, 8));
        // 2) update local running min (no global traffic in the loop)
        runmin[mi][j] = fminf(runmin[mi][j], rm);
        float thr = runmin[mi][j] + MARGIN;
        // 3) emit candidates into the per-block LDS buffer
#pragma unroll
        for (int ni = 0; ni < 2; ++ni) {
          if (d2a[ni][j] <= thr) {
            unsigned gv = (unsigned)(vbase + wc * 32 + ni * 16 + l15);
            unsigned ent = ((unsigned)grow << 13) | gv;
            unsigned pos = atomicAdd(&lcnt, 1u);
            if (pos < LCAP) {
              lbuf[pos] = ent;
            } else {           // rare overflow: direct global emission
              unsigned gp = atomicAdd(cnt, 1u);
              if (gp < cap) list[gp] = ent;
            }
          }
        }
      }
    }
    __syncthreads();
    // ---- MFMA 2: E += W * [C | 1]  (wave owns 16 rows x 144 cols) ----
#pragma unroll
    for (int kk = 0; kk < 2; ++kk) {
      bf16x8 awf = *(const bf16x8*)&wlds[w * 16 + l15][kk * 32 + lq * 8];
#pragma unroll
      for (int db = 0; db < 9; ++db) {
        int d = db * 16 + l15;
        int sqr = ((d >> 3) & 7) << 4;
        const char* tb = (const char*)&tileT[0][0];
        bf16x8 bw = *(const bf16x8*)(tb + d * 144 + (((kk * 32 + lq * 8) * 2) ^ sqr));
        eacc[db] = __builtin_amdgcn_mfma_f32_16x16x32_bf16(awf, bw, eacc[db], 0, 0, 0);
      }
    }
  }
  // ---- flush candidate list: ONE global atomic per block ----
  __syncthreads();
  unsigned total = lcnt < LCAP ? lcnt : LCAP;
  if (tid == 0) gbase = atomicAdd(cnt, total);
  __syncthreads();
  for (unsigned i = tid; i < total; i += 256) {
    unsigned p = gbase + i;
    if (p < cap) list[p] = lbuf[i];
  }
  // ---- flush embed partials ----
#pragma unroll
  for (int db = 0; db < 9; ++db) {
    int d = db * 16 + l15;
    if (d > 128) continue;
#pragma unroll
    for (int j = 0; j < 4; ++j) {
      int grow = blockRow + w * 16 + lq * 4 + j;
      atomicAdd(&accum[(size_t)grow * 129 + d], eacc[db][j]);
    }
  }
}

// ---------------- exact argmin fixup (fp64, one wave per candidate) ----------------
__global__ __launch_bounds__(256) void k_fix(const float* __restrict__ x,
                                             const float* __restrict__ cb,
                                             const unsigned int* __restrict__ list,
                                             const unsigned int* __restrict__ cnt,
                                             unsigned int cap,
                                             unsigned long long* __restrict__ kExact) {
  unsigned n = *cnt; if (n > cap) n = cap;
  int lane = threadIdx.x & 63;
  unsigned wave = blockIdx.x * (blockDim.x >> 6) + (threadIdx.x >> 6);
  unsigned nw = gridDim.x * (blockDim.x >> 6);
  for (unsigned e = wave; e < n; e += nw) {
    unsigned ent = list[e];
    unsigned row = ent >> 13;
    unsigned v = ent & 0x1FFFu;
    const float* xr = x + (size_t)row * DIM;
    const float* cr = cb + (size_t)v * DIM;
    float2 xa = *(const float2*)(xr + lane * 2);
    float2 ca = *(const float2*)(cr + lane * 2);
    double d0 = (double)xa.x - (double)ca.x;
    double d1 = (double)xa.y - (double)ca.y;
    double acc = d0 * d0 + d1 * d1;
    for (int off = 32; off; off >>= 1) acc += __shfl_down(acc, off);
    if (lane == 0)
      atomicMin(&kExact[row],
                ((unsigned long long)__float_as_uint((float)acc) << 32) | (unsigned long long)v);
  }
}

// ---------------- overflow rescue: full exact scan, one wave per row ----------------
__global__ __launch_bounds__(256) void k_rescue(const float* __restrict__ x,
                                                const float* __restrict__ cb,
                                                const unsigned int* __restrict__ cnt,
                                                unsigned int cap,
                                                unsigned long long* __restrict__ kExact) {
  if (*cnt <= cap) return;   // uniform early-out: rescue only needed on list overflow
  __shared__ float xs[4][128];
  int lane = threadIdx.x & 63;
  int wv = threadIdx.x >> 6;
  int row = blockIdx.x * 4 + wv;
  float2 xa = *(const float2*)(x + (size_t)row * DIM + lane * 2);
  xs[wv][lane * 2] = xa.x;
  xs[wv][lane * 2 + 1] = xa.y;
  __syncthreads();
  unsigned long long best = ~0ull;
  for (int v0 = 0; v0 < VOCAB; v0 += 64) {
    int v = v0 + lane;
    const float* cr = cb + (size_t)v * DIM;
    double acc = 0.0;
    for (int d = 0; d < DIM; ++d) {
      double diff = (double)xs[wv][d] - (double)cr[d];
      acc = fma(diff, diff, acc);
    }
    unsigned long long p = ((unsigned long long)__float_as_uint((float)acc) << 32)
                         | (unsigned long long)(unsigned)v;
    best = (p < best) ? p : best;
  }
#pragma unroll
  for (int off = 32; off; off >>= 1) {
    unsigned long long o = __shfl_xor(best, off);
    best = (o < best) ? o : best;
  }
  if (lane == 0) atomicMin(&kExact[row], best);
}

// ---------------- finalize ----------------
__global__ __launch_bounds__(256) void k_emb(const float* __restrict__ accum,
                                             float* __restrict__ out) {
  int i = blockIdx.x * 256 + threadIdx.x;
  int row = i >> 7, d = i & 127;
  float s = accum[(size_t)row * 129 + 128];
  out[i] = accum[(size_t)row * 129 + d] / s;
}

__global__ __launch_bounds__(256) void k_idx(const unsigned long long* __restrict__ kExact,
                                             float* __restrict__ out) {
  int n = blockIdx.x * 256 + threadIdx.x;
  out[EMB_ELEMS + n] = (float)(unsigned)(kExact[n] & 0x1FFFu);
}

extern "C" void kernel_launch(void* const* d_in, const int* in_sizes, int n_in,
                              void* d_out, int out_size, void* d_ws, size_t ws_size,
                              hipStream_t stream) {
  const float* x = (const float*)d_in[0];
  const float* cb = (const float*)d_in[1];
  float* out = (float*)d_out;

  char* ws = (char*)d_ws;
  size_t off = 0;
  float* accum = (float*)(ws + off); off += (size_t)NROWS * 129 * 4;
  float* c2 = (float*)(ws + off); off += (size_t)VOCAB * 4;
  unsigned short* cbf = (unsigned short*)(ws + off); off += (size_t)VOCAB * DIM * 2;
  unsigned long long* kExact = (unsigned long long*)(ws + off); off += (size_t)NROWS * 8;
  unsigned int* cnt = (unsigned int*)(ws + off); off += 64;
  unsigned int* list = (unsigned int*)(ws + off);
  size_t cap32 = (ws_size > off) ? (ws_size - off) / 4 : 0;
  unsigned cap = (unsigned)(cap32 > LIST_CAP_MAX ? LIST_CAP_MAX : cap32);

  hipMemsetAsync(accum, 0, (size_t)NROWS * 129 * 4, stream);
  hipMemsetAsync(kExact, 0xFF, (size_t)NROWS * 8, stream);
  hipMemsetAsync(cnt, 0, 64, stream);

  k_prep<<<VOCAB / 16, 256, 0, stream>>>(cb, c2, cbf);
  k_main<<<dim3(NROWS / BN, VSPLITS), 256, 0, stream>>>(x, c2, cbf, accum, cnt, list, cap);
  k_fix<<<1024, 256, 0, stream>>>(x, cb, list, cnt, cap, kExact);
  k_rescue<<<NROWS / 4, 256, 0, stream>>>(x, cb, cnt, cap, kExact);
  k_emb<<<EMB_ELEMS / 256, 256, 0, stream>>>(accum, out);
  k_idx<<<NROWS / 256, 256, 0, stream>>>(kExact, out);
}

// Round 7
// 343.911 us; speedup vs baseline: 4.3716x; 1.5252x over previous
//
#include <hip/hip_runtime.h>
#include <stdint.h>

#define NROWS 16384
#define DIM   128
#define VOCAB 8192
#define BN 64
#define BV 64
#define VSPLITS 4
#define SPLITV (VOCAB / VSPLITS)   /* 2048 */
#define NTILES (SPLITV / BV)       /* 32 */
#define MARGIN  0.8f
#define EMB_ELEMS (NROWS * DIM)    /* 2097152 */
#define LIST_CAP_MAX 4194304u
#define LCAP 512

typedef __attribute__((ext_vector_type(8))) short bf16x8;
typedef __attribute__((ext_vector_type(4))) float f32x4;

__device__ __forceinline__ unsigned short f2bf(float f) {
  union { float f; unsigned u; } v; v.f = f;
  unsigned r = v.u + 0x7fffu + ((v.u >> 16) & 1u);
  return (unsigned short)(r >> 16);
}

__device__ __forceinline__ bf16x8 pack8(float4 a, float4 b) {
  bf16x8 r;
  r[0] = (short)f2bf(a.x); r[1] = (short)f2bf(a.y);
  r[2] = (short)f2bf(a.z); r[3] = (short)f2bf(a.w);
  r[4] = (short)f2bf(b.x); r[5] = (short)f2bf(b.y);
  r[6] = (short)f2bf(b.z); r[7] = (short)f2bf(b.w);
  return r;
}

// ---------------- prep: c2 = ||c||^2 (fp32), cbf = bf16(codebook) ----------------
__global__ __launch_bounds__(256) void k_prep(const float* __restrict__ cb,
                                              float* __restrict__ c2,
                                              unsigned short* __restrict__ cbf) {
  int tid = threadIdx.x;
  int r = blockIdx.x * 16 + (tid >> 4);
  int l = tid & 15;
  const float* rp = cb + (size_t)r * DIM + l * 8;
  float4 a = *(const float4*)rp;
  float4 b = *(const float4*)(rp + 4);
  float s = a.x*a.x + a.y*a.y + a.z*a.z + a.w*a.w
          + b.x*b.x + b.y*b.y + b.z*b.z + b.w*b.w;
  bf16x8 v8 = pack8(a, b);
  *(bf16x8*)(cbf + (size_t)r * DIM + l * 8) = v8;
#pragma unroll
  for (int o = 1; o < 16; o <<= 1) s += __shfl_xor(s, o);
  if (l == 0) c2[r] = s;
}

// ---------------- main fused kernel ----------------
// Wave w owns output rows m = blockRow + w*16 + (lane&15), all 64 v of each tile.
// MFMA1 (swapped): S^T[v][m] = mfma(A=C[v][d], B=X^T[d][m]).
//   lane (l15,lq): sacc[vi][j] = S^T[vi*16+lq*4+j][m=l15]
// Weights stay in-register; MFMA2 A-frag built via pack + ds_bpermute.
__global__ __launch_bounds__(256, 4) void k_main(
    const float* __restrict__ x, const float* __restrict__ c2g,
    const unsigned short* __restrict__ cbf,
    float* __restrict__ accum,                  // [NROWS][129] (num | s)
    unsigned int* __restrict__ cnt,
    unsigned int* __restrict__ list, unsigned int cap) {
  __shared__ unsigned short tile1[BV][136];   // codebook tile, row-major [v][d]
  __shared__ unsigned short tileT[DIM][72];   // transposed [d][v], XOR-swizzled
  __shared__ unsigned int lbuf[LCAP];
  __shared__ unsigned int lcnt;
  __shared__ unsigned int gbase;

  const int tid = threadIdx.x;
  const int lane = tid & 63;
  const int w = tid >> 6;               // wave 0..3 -> m-quarter
  const int l15 = lane & 15, lq = lane >> 4;
  const int blockRow = blockIdx.x * BN;
  const int vy = blockIdx.y;

  if (tid == 0) lcnt = 0;

  // preload x fragments (B-operand of MFMA1): x[m = blockRow + w*16 + l15][.]
  bf16x8 afrag[4];
  float x2 = 0.f;
  {
    int gr = blockRow + w * 16 + l15;
    const float* xr = x + (size_t)gr * DIM + lq * 8;
#pragma unroll
    for (int kf = 0; kf < 4; ++kf) {
      float4 a = *(const float4*)(xr + kf * 32);
      float4 b = *(const float4*)(xr + kf * 32 + 4);
      x2 += a.x*a.x + a.y*a.y + a.z*a.z + a.w*a.w
          + b.x*b.x + b.y*b.y + b.z*b.z + b.w*b.w;
      afrag[kf] = pack8(a, b);
    }
    x2 += __shfl_xor(x2, 16);
    x2 += __shfl_xor(x2, 32);   // x2 = ||x[m]||^2, m = w*16+l15
  }

  f32x4 eacc[8];
#pragma unroll
  for (int db = 0; db < 8; ++db) eacc[db] = (f32x4){0.f, 0.f, 0.f, 0.f};
  float den = 0.f;
  float runminD = 3.0e19f;    // running min DIST (not d2)

  // staging assignment: 4 v-rows x 8 d per thread
  const int sv = (tid >> 4) * 4;    // 0..60
  const int sd = (tid & 15) * 8;    // 0..120
  const int sS = (tid & 7) << 4;    // S(d) = ((d>>3)&7)<<4 for this thread's 8 d's

  // bpermute byte-indices: srcA = lane l15 + 32*(lq&1); srcB = srcA + 16
  const int srcA = (l15 + ((lane & 16) << 1)) << 2;
  const int srcB = srcA + 64;

  for (int it = 0; it < NTILES; ++it) {
    int vbase = vy * SPLITV + it * BV;
    __syncthreads();   // previous tile's reads done
    // ---- stage codebook tile: tile1 row-major + tileT transposed ----
    {
      uint4 r0 = *(const uint4*)(cbf + (size_t)(vbase + sv + 0) * DIM + sd);
      uint4 r1 = *(const uint4*)(cbf + (size_t)(vbase + sv + 1) * DIM + sd);
      uint4 r2 = *(const uint4*)(cbf + (size_t)(vbase + sv + 2) * DIM + sd);
      uint4 r3 = *(const uint4*)(cbf + (size_t)(vbase + sv + 3) * DIM + sd);
      *(uint4*)&tile1[sv + 0][sd] = r0;
      *(uint4*)&tile1[sv + 1][sd] = r1;
      *(uint4*)&tile1[sv + 2][sd] = r2;
      *(uint4*)&tile1[sv + 3][sd] = r3;
      const unsigned short* s0 = (const unsigned short*)&r0;
      const unsigned short* s1 = (const unsigned short*)&r1;
      const unsigned short* s2 = (const unsigned short*)&r2;
      const unsigned short* s3 = (const unsigned short*)&r3;
      char* tb = (char*)&tileT[0][0];
#pragma unroll
      for (int k = 0; k < 8; ++k) {
        uint2 val;
        val.x = (unsigned)s0[k] | ((unsigned)s1[k] << 16);
        val.y = (unsigned)s2[k] | ((unsigned)s3[k] << 16);
        *(uint2*)(tb + (sd + k) * 144 + ((sv * 2) ^ sS)) = val;
      }
    }
    // c2 fragments (L2-resident, overlaps staging)
    float4 c2v0 = *(const float4*)(c2g + vbase + 0 * 16 + lq * 4);
    float4 c2v1 = *(const float4*)(c2g + vbase + 1 * 16 + lq * 4);
    float4 c2v2 = *(const float4*)(c2g + vbase + 2 * 16 + lq * 4);
    float4 c2v3 = *(const float4*)(c2g + vbase + 3 * 16 + lq * 4);
    __syncthreads();
    // ---- MFMA 1: S^T = C * X^T  (wave: 64v x 16m) ----
    f32x4 sacc[4];
#pragma unroll
    for (int vi = 0; vi < 4; ++vi) sacc[vi] = (f32x4){0.f, 0.f, 0.f, 0.f};
#pragma unroll
    for (int kf = 0; kf < 4; ++kf) {
#pragma unroll
      for (int vi = 0; vi < 4; ++vi) {
        bf16x8 cf = *(const bf16x8*)&tile1[vi * 16 + l15][kf * 32 + lq * 8];
        sacc[vi] = __builtin_amdgcn_mfma_f32_16x16x32_bf16(cf, afrag[kf], sacc[vi], 0, 0, 0);
      }
    }
    // ---- d2 -> dist (f32, stays in regs) ----
    float dd[4][4];
    const float* c2p[4] = {&c2v0.x, &c2v1.x, &c2v2.x, &c2v3.x};
#pragma unroll
    for (int vi = 0; vi < 4; ++vi)
#pragma unroll
      for (int j = 0; j < 4; ++j) {
        float d2 = fmaxf(fmaf(-2.f, sacc[vi][j], x2 + c2p[vi][j]), 0.f);
        float dist = sqrtf(d2) + 1e-8f;
        dd[vi][j] = dist;
        den += dist;
      }
    // ---- tile min over this lane's 16 + across lq lanes (same m) ----
    float rm = dd[0][0];
#pragma unroll
    for (int vi = 0; vi < 4; ++vi)
#pragma unroll
      for (int j = 0; j < 4; ++j) rm = fminf(rm, dd[vi][j]);
    rm = fminf(rm, __shfl_xor(rm, 16));
    rm = fminf(rm, __shfl_xor(rm, 32));
    runminD = fminf(runminD, rm);
    float thrD = sqrtf(fmaf(runminD, runminD, MARGIN)) + 2e-8f;
    // ---- emit candidates ----
    {
      unsigned grow = (unsigned)(blockRow + w * 16 + l15);
#pragma unroll
      for (int vi = 0; vi < 4; ++vi)
#pragma unroll
        for (int j = 0; j < 4; ++j) {
          if (dd[vi][j] <= thrD) {
            unsigned gv = (unsigned)(vbase + vi * 16 + lq * 4 + j);
            unsigned ent = (grow << 13) | gv;
            unsigned pos = atomicAdd(&lcnt, 1u);
            if (pos < LCAP) {
              lbuf[pos] = ent;
            } else {
              unsigned gp = atomicAdd(cnt, 1u);
              if (gp < cap) list[gp] = ent;
            }
          }
        }
    }
    // ---- pack weights to bf16 pairs: wlo/whi[vi] = (j0|j1<<16), (j2|j3<<16) ----
    int wlo[4], whi[4];
#pragma unroll
    for (int vi = 0; vi < 4; ++vi) {
      wlo[vi] = (int)((unsigned)f2bf(dd[vi][0]) | ((unsigned)f2bf(dd[vi][1]) << 16));
      whi[vi] = (int)((unsigned)f2bf(dd[vi][2]) | ((unsigned)f2bf(dd[vi][3]) << 16));
    }
    // ---- MFMA 2: E[m][d] += W[m][v] * C[v][d], 2 k-steps of 32 v ----
    const char* tb = (const char*)&tileT[0][0];
#pragma unroll
    for (int ks = 0; ks < 2; ++ks) {
      int v0 = ks * 2, v1 = ks * 2 + 1;
      int t0, t1;
      union { int u[4]; bf16x8 v8; } A;
      t0 = __builtin_amdgcn_ds_bpermute(srcA, wlo[v0]);
      t1 = __builtin_amdgcn_ds_bpermute(srcA, wlo[v1]);
      A.u[0] = (lq & 2) ? t1 : t0;
      t0 = __builtin_amdgcn_ds_bpermute(srcA, whi[v0]);
      t1 = __builtin_amdgcn_ds_bpermute(srcA, whi[v1]);
      A.u[1] = (lq & 2) ? t1 : t0;
      t0 = __builtin_amdgcn_ds_bpermute(srcB, wlo[v0]);
      t1 = __builtin_amdgcn_ds_bpermute(srcB, wlo[v1]);
      A.u[2] = (lq & 2) ? t1 : t0;
      t0 = __builtin_amdgcn_ds_bpermute(srcB, whi[v0]);
      t1 = __builtin_amdgcn_ds_bpermute(srcB, whi[v1]);
      A.u[3] = (lq & 2) ? t1 : t0;
      int voff = (ks * 32 + lq * 8) * 2;
#pragma unroll
      for (int db = 0; db < 8; ++db) {
        int d = db * 16 + l15;
        bf16x8 bw = *(const bf16x8*)(tb + d * 144 + (voff ^ (((d >> 3) & 7) << 4)));
        eacc[db] = __builtin_amdgcn_mfma_f32_16x16x32_bf16(A.v8, bw, eacc[db], 0, 0, 0);
      }
    }
  }
  // ---- flush candidate list: ONE global atomic per block ----
  __syncthreads();
  unsigned total = lcnt < LCAP ? lcnt : LCAP;
  if (tid == 0) gbase = atomicAdd(cnt, total);
  __syncthreads();
  for (unsigned i = tid; i < total; i += 256) {
    unsigned p = gbase + i;
    if (p < cap) list[p] = lbuf[i];
  }
  // ---- flush embed partials: E[m = blockRow+w*16+lq*4+j][d = db*16+l15] ----
#pragma unroll
  for (int db = 0; db < 8; ++db) {
#pragma unroll
    for (int j = 0; j < 4; ++j) {
      int grow = blockRow + w * 16 + lq * 4 + j;
      atomicAdd(&accum[(size_t)grow * 129 + db * 16 + l15], eacc[db][j]);
    }
  }
  // ---- flush denominator (per m = l15 of this wave) ----
  den += __shfl_xor(den, 16);
  den += __shfl_xor(den, 32);
  if (lq == 0)
    atomicAdd(&accum[(size_t)(blockRow + w * 16 + l15) * 129 + 128], den);
}

// ---------------- exact argmin fixup (fp64, one wave per candidate) ----------------
__global__ __launch_bounds__(256) void k_fix(const float* __restrict__ x,
                                             const float* __restrict__ cb,
                                             const unsigned int* __restrict__ list,
                                             const unsigned int* __restrict__ cnt,
                                             unsigned int cap,
                                             unsigned long long* __restrict__ kExact) {
  unsigned n = *cnt; if (n > cap) n = cap;
  int lane = threadIdx.x & 63;
  unsigned wave = blockIdx.x * (blockDim.x >> 6) + (threadIdx.x >> 6);
  unsigned nw = gridDim.x * (blockDim.x >> 6);
  for (unsigned e = wave; e < n; e += nw) {
    unsigned ent = list[e];
    unsigned row = ent >> 13;
    unsigned v = ent & 0x1FFFu;
    const float* xr = x + (size_t)row * DIM;
    const float* cr = cb + (size_t)v * DIM;
    float2 xa = *(const float2*)(xr + lane * 2);
    float2 ca = *(const float2*)(cr + lane * 2);
    double d0 = (double)xa.x - (double)ca.x;
    double d1 = (double)xa.y - (double)ca.y;
    double acc = d0 * d0 + d1 * d1;
    for (int off = 32; off; off >>= 1) acc += __shfl_down(acc, off);
    if (lane == 0)
      atomicMin(&kExact[row],
                ((unsigned long long)__float_as_uint((float)acc) << 32) | (unsigned long long)v);
  }
}

// ---------------- overflow rescue: full exact scan, one wave per row ----------------
__global__ __launch_bounds__(256) void k_rescue(const float* __restrict__ x,
                                                const float* __restrict__ cb,
                                                const unsigned int* __restrict__ cnt,
                                                unsigned int cap,
                                                unsigned long long* __restrict__ kExact) {
  if (*cnt <= cap) return;   // uniform early-out: rescue only needed on list overflow
  __shared__ float xs[4][128];
  int lane = threadIdx.x & 63;
  int wv = threadIdx.x >> 6;
  int row = blockIdx.x * 4 + wv;
  float2 xa = *(const float2*)(x + (size_t)row * DIM + lane * 2);
  xs[wv][lane * 2] = xa.x;
  xs[wv][lane * 2 + 1] = xa.y;
  __syncthreads();
  unsigned long long best = ~0ull;
  for (int v0 = 0; v0 < VOCAB; v0 += 64) {
    int v = v0 + lane;
    const float* cr = cb + (size_t)v * DIM;
    double acc = 0.0;
    for (int d = 0; d < DIM; ++d) {
      double diff = (double)xs[wv][d] - (double)cr[d];
      acc = fma(diff, diff, acc);
    }
    unsigned long long p = ((unsigned long long)__float_as_uint((float)acc) << 32)
                         | (unsigned long long)(unsigned)v;
    best = (p < best) ? p : best;
  }
#pragma unroll
  for (int off = 32; off; off >>= 1) {
    unsigned long long o = __shfl_xor(best, off);
    best = (o < best) ? o : best;
  }
  if (lane == 0) atomicMin(&kExact[row], best);
}

// ---------------- finalize ----------------
__global__ __launch_bounds__(256) void k_emb(const float* __restrict__ accum,
                                             float* __restrict__ out) {
  int i = blockIdx.x * 256 + threadIdx.x;
  int row = i >> 7, d = i & 127;
  float s = accum[(size_t)row * 129 + 128];
  out[i] = accum[(size_t)row * 129 + d] / s;
}

__global__ __launch_bounds__(256) void k_idx(const unsigned long long* __restrict__ kExact,
                                             float* __restrict__ out) {
  int n = blockIdx.x * 256 + threadIdx.x;
  out[EMB_ELEMS + n] = (float)(unsigned)(kExact[n] & 0x1FFFu);
}

extern "C" void kernel_launch(void* const* d_in, const int* in_sizes, int n_in,
                              void* d_out, int out_size, void* d_ws, size_t ws_size,
                              hipStream_t stream) {
  const float* x = (const float*)d_in[0];
  const float* cb = (const float*)d_in[1];
  float* out = (float*)d_out;

  char* ws = (char*)d_ws;
  size_t off = 0;
  float* accum = (float*)(ws + off); off += (size_t)NROWS * 129 * 4;
  float* c2 = (float*)(ws + off); off += (size_t)VOCAB * 4;
  unsigned short* cbf = (unsigned short*)(ws + off); off += (size_t)VOCAB * DIM * 2;
  unsigned long long* kExact = (unsigned long long*)(ws + off); off += (size_t)NROWS * 8;
  unsigned int* cnt = (unsigned int*)(ws + off); off += 64;
  unsigned int* list = (unsigned int*)(ws + off);
  size_t cap32 = (ws_size > off) ? (ws_size - off) / 4 : 0;
  unsigned cap = (unsigned)(cap32 > LIST_CAP_MAX ? LIST_CAP_MAX : cap32);

  hipMemsetAsync(accum, 0, (size_t)NROWS * 129 * 4, stream);
  hipMemsetAsync(kExact, 0xFF, (size_t)NROWS * 8, stream);
  hipMemsetAsync(cnt, 0, 64, stream);

  k_prep<<<VOCAB / 16, 256, 0, stream>>>(cb, c2, cbf);
  k_main<<<dim3(NROWS / BN, VSPLITS), 256, 0, stream>>>(x, c2, cbf, accum, cnt, list, cap);
  k_fix<<<1024, 256, 0, stream>>>(x, cb, list, cnt, cap, kExact);
  k_rescue<<<NROWS / 4, 256, 0, stream>>>(x, cb, cnt, cap, kExact);
  k_emb<<<EMB_ELEMS / 256, 256, 0, stream>>>(accum, out);
  k_idx<<<NROWS / 256, 256, 0, stream>>>(kExact, out);
}

// Round 8
// 329.650 us; speedup vs baseline: 4.5607x; 1.0433x over previous
//
#include <hip/hip_runtime.h>
#include <stdint.h>

#define NROWS 16384
#define DIM   128
#define VOCAB 8192
#define BN 64
#define BV 64
#define VSPLITS 4
#define SPLITV (VOCAB / VSPLITS)   /* 2048 */
#define NTILES (SPLITV / BV)       /* 32 */
#define MARGIN  0.8f
#define EMB_ELEMS (NROWS * DIM)    /* 2097152 */
#define LIST_CAP_MAX 4194304u
#define LCAP 512

typedef __attribute__((ext_vector_type(8))) short bf16x8;
typedef __attribute__((ext_vector_type(4))) float f32x4;

__device__ __forceinline__ unsigned short f2bf(float f) {
  union { float f; unsigned u; } v; v.f = f;
  unsigned r = v.u + 0x7fffu + ((v.u >> 16) & 1u);
  return (unsigned short)(r >> 16);
}

__device__ __forceinline__ int cvt_pk_bf16(float lo, float hi) {
  int r;
  asm("v_cvt_pk_bf16_f32 %0, %1, %2" : "=v"(r) : "v"(lo), "v"(hi));
  return r;
}

__device__ __forceinline__ bf16x8 pack8(float4 a, float4 b) {
  bf16x8 r;
  r[0] = (short)f2bf(a.x); r[1] = (short)f2bf(a.y);
  r[2] = (short)f2bf(a.z); r[3] = (short)f2bf(a.w);
  r[4] = (short)f2bf(b.x); r[5] = (short)f2bf(b.y);
  r[6] = (short)f2bf(b.z); r[7] = (short)f2bf(b.w);
  return r;
}

// ---------------- prep: c2 = ||c||^2 (fp32), cbf = bf16(codebook) ----------------
__global__ __launch_bounds__(256) void k_prep(const float* __restrict__ cb,
                                              float* __restrict__ c2,
                                              unsigned short* __restrict__ cbf) {
  int tid = threadIdx.x;
  int r = blockIdx.x * 16 + (tid >> 4);
  int l = tid & 15;
  const float* rp = cb + (size_t)r * DIM + l * 8;
  float4 a = *(const float4*)rp;
  float4 b = *(const float4*)(rp + 4);
  float s = a.x*a.x + a.y*a.y + a.z*a.z + a.w*a.w
          + b.x*b.x + b.y*b.y + b.z*b.z + b.w*b.w;
  bf16x8 v8 = pack8(a, b);
  *(bf16x8*)(cbf + (size_t)r * DIM + l * 8) = v8;
#pragma unroll
  for (int o = 1; o < 16; o <<= 1) s += __shfl_xor(s, o);
  if (l == 0) c2[r] = s;
}

// ---------------- main fused kernel ----------------
// Wave w owns output rows m = blockRow + w*16 + (lane&15), all 64 v of each tile.
// MFMA1 (swapped): S^T[v][m] = mfma(A=C[v][d], B=X^T[d][m]).
//   lane (l15,lq): sacc[vi][j] = S^T[vi*16+lq*4+j][m=l15]
// Weights stay in-register; MFMA2 A-frag built via cvt_pk + ds_bpermute.
__global__ __launch_bounds__(256, 4) void k_main(
    const float* __restrict__ x, const float* __restrict__ c2g,
    const unsigned short* __restrict__ cbf,
    float* __restrict__ accum,                  // [NROWS][129] (num | s)
    unsigned int* __restrict__ cnt,
    unsigned int* __restrict__ list, unsigned int cap) {
  __shared__ unsigned short tile1[BV][136];   // codebook tile, row-major [v][d]
  __shared__ unsigned short tileT[DIM][72];   // transposed [d][v], XOR-swizzled
  __shared__ unsigned int lbuf[LCAP];
  __shared__ unsigned int lcnt;
  __shared__ unsigned int gbase;

  const int tid = threadIdx.x;
  const int lane = tid & 63;
  const int w = tid >> 6;               // wave 0..3 -> m-quarter
  const int l15 = lane & 15, lq = lane >> 4;
  const int blockRow = blockIdx.x * BN;
  const int vy = blockIdx.y;

  if (tid == 0) lcnt = 0;

  // preload x fragments (B-operand of MFMA1): x[m = blockRow + w*16 + l15][.]
  bf16x8 afrag[4];
  float x2 = 0.f;
  {
    int gr = blockRow + w * 16 + l15;
    const float* xr = x + (size_t)gr * DIM + lq * 8;
#pragma unroll
    for (int kf = 0; kf < 4; ++kf) {
      float4 a = *(const float4*)(xr + kf * 32);
      float4 b = *(const float4*)(xr + kf * 32 + 4);
      x2 += a.x*a.x + a.y*a.y + a.z*a.z + a.w*a.w
          + b.x*b.x + b.y*b.y + b.z*b.z + b.w*b.w;
      afrag[kf] = pack8(a, b);
    }
    x2 += __shfl_xor(x2, 16);
    x2 += __shfl_xor(x2, 32);   // x2 = ||x[m]||^2, m = w*16+l15
  }

  f32x4 eacc[8];
#pragma unroll
  for (int db = 0; db < 8; ++db) eacc[db] = (f32x4){0.f, 0.f, 0.f, 0.f};
  float den = 0.f;
  float runminD = 3.0e19f;    // running min DIST (not d2)

  // staging assignment: 4 v-rows x 8 d per thread
  const int sv = (tid >> 4) * 4;    // 0..60
  const int sd = (tid & 15) * 8;    // 0..120
  const int sS = (tid & 7) << 4;    // S(d) = ((d>>3)&7)<<4 for this thread's 8 d's

  // bpermute byte-indices: srcA = lane l15 + 32*(lq&1); srcB = srcA + 16
  const int srcA = (l15 + ((lane & 16) << 1)) << 2;
  const int srcB = srcA + 64;

  for (int it = 0; it < NTILES; ++it) {
    int vbase = vy * SPLITV + it * BV;
    __syncthreads();   // previous tile's reads done
    // ---- stage codebook tile: tile1 row-major + tileT transposed ----
    {
      uint4 r0 = *(const uint4*)(cbf + (size_t)(vbase + sv + 0) * DIM + sd);
      uint4 r1 = *(const uint4*)(cbf + (size_t)(vbase + sv + 1) * DIM + sd);
      uint4 r2 = *(const uint4*)(cbf + (size_t)(vbase + sv + 2) * DIM + sd);
      uint4 r3 = *(const uint4*)(cbf + (size_t)(vbase + sv + 3) * DIM + sd);
      *(uint4*)&tile1[sv + 0][sd] = r0;
      *(uint4*)&tile1[sv + 1][sd] = r1;
      *(uint4*)&tile1[sv + 2][sd] = r2;
      *(uint4*)&tile1[sv + 3][sd] = r3;
      const unsigned short* s0 = (const unsigned short*)&r0;
      const unsigned short* s1 = (const unsigned short*)&r1;
      const unsigned short* s2 = (const unsigned short*)&r2;
      const unsigned short* s3 = (const unsigned short*)&r3;
      char* tb = (char*)&tileT[0][0];
#pragma unroll
      for (int k = 0; k < 8; ++k) {
        uint2 val;
        val.x = (unsigned)s0[k] | ((unsigned)s1[k] << 16);
        val.y = (unsigned)s2[k] | ((unsigned)s3[k] << 16);
        *(uint2*)(tb + (sd + k) * 144 + ((sv * 2) ^ sS)) = val;
      }
    }
    // c2 fragments (L2-resident, overlaps staging)
    float4 c2v0 = *(const float4*)(c2g + vbase + 0 * 16 + lq * 4);
    float4 c2v1 = *(const float4*)(c2g + vbase + 1 * 16 + lq * 4);
    float4 c2v2 = *(const float4*)(c2g + vbase + 2 * 16 + lq * 4);
    float4 c2v3 = *(const float4*)(c2g + vbase + 3 * 16 + lq * 4);
    __syncthreads();
    // ---- MFMA 1: S^T = C * X^T  (wave: 64v x 16m) ----
    f32x4 sacc[4];
#pragma unroll
    for (int vi = 0; vi < 4; ++vi) sacc[vi] = (f32x4){0.f, 0.f, 0.f, 0.f};
#pragma unroll
    for (int kf = 0; kf < 4; ++kf) {
#pragma unroll
      for (int vi = 0; vi < 4; ++vi) {
        bf16x8 cf = *(const bf16x8*)&tile1[vi * 16 + l15][kf * 32 + lq * 8];
        sacc[vi] = __builtin_amdgcn_mfma_f32_16x16x32_bf16(cf, afrag[kf], sacc[vi], 0, 0, 0);
      }
    }
    // ---- d2 -> dist (f32, stays in regs) ----
    float dd[4][4];
    const float* c2p[4] = {&c2v0.x, &c2v1.x, &c2v2.x, &c2v3.x};
#pragma unroll
    for (int vi = 0; vi < 4; ++vi)
#pragma unroll
      for (int j = 0; j < 4; ++j) {
        float d2 = fmaxf(fmaf(-2.f, sacc[vi][j], x2 + c2p[vi][j]), 0.f);
        float dist = sqrtf(d2) + 1e-8f;
        dd[vi][j] = dist;
        den += dist;
      }
    // ---- tile min over this lane's 16 + across lq lanes (same m) ----
    float rm = dd[0][0];
#pragma unroll
    for (int vi = 0; vi < 4; ++vi)
#pragma unroll
      for (int j = 0; j < 4; ++j) rm = fminf(rm, dd[vi][j]);
    rm = fminf(rm, __shfl_xor(rm, 16));
    rm = fminf(rm, __shfl_xor(rm, 32));
    runminD = fminf(runminD, rm);
    float thrD = sqrtf(fmaf(runminD, runminD, MARGIN)) + 2e-8f;
    // ---- emit candidates (wave-any gate: skip the 16-compare block
    //      unless some row of this wave has a tile-min within margin) ----
    if (__any(rm <= thrD)) {
      unsigned grow = (unsigned)(blockRow + w * 16 + l15);
#pragma unroll
      for (int vi = 0; vi < 4; ++vi)
#pragma unroll
        for (int j = 0; j < 4; ++j) {
          if (dd[vi][j] <= thrD) {
            unsigned gv = (unsigned)(vbase + vi * 16 + lq * 4 + j);
            unsigned ent = (grow << 13) | gv;
            unsigned pos = atomicAdd(&lcnt, 1u);
            if (pos < LCAP) {
              lbuf[pos] = ent;
            } else {
              unsigned gp = atomicAdd(cnt, 1u);
              if (gp < cap) list[gp] = ent;
            }
          }
        }
    }
    // ---- pack weights to bf16 pairs via v_cvt_pk_bf16_f32 ----
    int wlo[4], whi[4];
#pragma unroll
    for (int vi = 0; vi < 4; ++vi) {
      wlo[vi] = cvt_pk_bf16(dd[vi][0], dd[vi][1]);
      whi[vi] = cvt_pk_bf16(dd[vi][2], dd[vi][3]);
    }
    // ---- MFMA 2: E[m][d] += W[m][v] * C[v][d], 2 k-steps of 32 v ----
    const char* tb = (const char*)&tileT[0][0];
#pragma unroll
    for (int ks = 0; ks < 2; ++ks) {
      int v0 = ks * 2, v1 = ks * 2 + 1;
      int t0, t1;
      union { int u[4]; bf16x8 v8; } A;
      t0 = __builtin_amdgcn_ds_bpermute(srcA, wlo[v0]);
      t1 = __builtin_amdgcn_ds_bpermute(srcA, wlo[v1]);
      A.u[0] = (lq & 2) ? t1 : t0;
      t0 = __builtin_amdgcn_ds_bpermute(srcA, whi[v0]);
      t1 = __builtin_amdgcn_ds_bpermute(srcA, whi[v1]);
      A.u[1] = (lq & 2) ? t1 : t0;
      t0 = __builtin_amdgcn_ds_bpermute(srcB, wlo[v0]);
      t1 = __builtin_amdgcn_ds_bpermute(srcB, wlo[v1]);
      A.u[2] = (lq & 2) ? t1 : t0;
      t0 = __builtin_amdgcn_ds_bpermute(srcB, whi[v0]);
      t1 = __builtin_amdgcn_ds_bpermute(srcB, whi[v1]);
      A.u[3] = (lq & 2) ? t1 : t0;
      int voff = (ks * 32 + lq * 8) * 2;
#pragma unroll
      for (int db = 0; db < 8; ++db) {
        int d = db * 16 + l15;
        bf16x8 bw = *(const bf16x8*)(tb + d * 144 + (voff ^ (((d >> 3) & 7) << 4)));
        eacc[db] = __builtin_amdgcn_mfma_f32_16x16x32_bf16(A.v8, bw, eacc[db], 0, 0, 0);
      }
    }
  }
  // ---- flush candidate list: ONE global atomic per block ----
  __syncthreads();
  unsigned total = lcnt < LCAP ? lcnt : LCAP;
  if (tid == 0) gbase = atomicAdd(cnt, total);
  __syncthreads();
  for (unsigned i = tid; i < total; i += 256) {
    unsigned p = gbase + i;
    if (p < cap) list[p] = lbuf[i];
  }
  // ---- flush embed partials: E[m = blockRow+w*16+lq*4+j][d = db*16+l15] ----
#pragma unroll
  for (int db = 0; db < 8; ++db) {
#pragma unroll
    for (int j = 0; j < 4; ++j) {
      int grow = blockRow + w * 16 + lq * 4 + j;
      atomicAdd(&accum[(size_t)grow * 129 + db * 16 + l15], eacc[db][j]);
    }
  }
  // ---- flush denominator (per m = l15 of this wave) ----
  den += __shfl_xor(den, 16);
  den += __shfl_xor(den, 32);
  if (lq == 0)
    atomicAdd(&accum[(size_t)(blockRow + w * 16 + l15) * 129 + 128], den);
}

// ---------------- exact argmin fixup (fp64, one wave per candidate) ----------------
__global__ __launch_bounds__(256) void k_fix(const float* __restrict__ x,
                                             const float* __restrict__ cb,
                                             const unsigned int* __restrict__ list,
                                             const unsigned int* __restrict__ cnt,
                                             unsigned int cap,
                                             unsigned long long* __restrict__ kExact) {
  unsigned n = *cnt; if (n > cap) n = cap;
  int lane = threadIdx.x & 63;
  unsigned wave = blockIdx.x * (blockDim.x >> 6) + (threadIdx.x >> 6);
  unsigned nw = gridDim.x * (blockDim.x >> 6);
  for (unsigned e = wave; e < n; e += nw) {
    unsigned ent = list[e];
    unsigned row = ent >> 13;
    unsigned v = ent & 0x1FFFu;
    const float* xr = x + (size_t)row * DIM;
    const float* cr = cb + (size_t)v * DIM;
    float2 xa = *(const float2*)(xr + lane * 2);
    float2 ca = *(const float2*)(cr + lane * 2);
    double d0 = (double)xa.x - (double)ca.x;
    double d1 = (double)xa.y - (double)ca.y;
    double acc = d0 * d0 + d1 * d1;
    for (int off = 32; off; off >>= 1) acc += __shfl_down(acc, off);
    if (lane == 0)
      atomicMin(&kExact[row],
                ((unsigned long long)__float_as_uint((float)acc) << 32) | (unsigned long long)v);
  }
}

// ---------------- overflow rescue: full exact scan, one wave per row ----------------
__global__ __launch_bounds__(256) void k_rescue(const float* __restrict__ x,
                                                const float* __restrict__ cb,
                                                const unsigned int* __restrict__ cnt,
                                                unsigned int cap,
                                                unsigned long long* __restrict__ kExact) {
  if (*cnt <= cap) return;   // uniform early-out: rescue only needed on list overflow
  __shared__ float xs[4][128];
  int lane = threadIdx.x & 63;
  int wv = threadIdx.x >> 6;
  int row = blockIdx.x * 4 + wv;
  float2 xa = *(const float2*)(x + (size_t)row * DIM + lane * 2);
  xs[wv][lane * 2] = xa.x;
  xs[wv][lane * 2 + 1] = xa.y;
  __syncthreads();
  unsigned long long best = ~0ull;
  for (int v0 = 0; v0 < VOCAB; v0 += 64) {
    int v = v0 + lane;
    const float* cr = cb + (size_t)v * DIM;
    double acc = 0.0;
    for (int d = 0; d < DIM; ++d) {
      double diff = (double)xs[wv][d] - (double)cr[d];
      acc = fma(diff, diff, acc);
    }
    unsigned long long p = ((unsigned long long)__float_as_uint((float)acc) << 32)
                         | (unsigned long long)(unsigned)v;
    best = (p < best) ? p : best;
  }
#pragma unroll
  for (int off = 32; off; off >>= 1) {
    unsigned long long o = __shfl_xor(best, off);
    best = (o < best) ? o : best;
  }
  if (lane == 0) atomicMin(&kExact[row], best);
}

// ---------------- finalize: embed normalize + idx cast (merged) ----------------
__global__ __launch_bounds__(256) void k_out(const float* __restrict__ accum,
                                             const unsigned long long* __restrict__ kExact,
                                             float* __restrict__ out) {
  int i = blockIdx.x * 256 + threadIdx.x;
  if (i < EMB_ELEMS) {
    int row = i >> 7, d = i & 127;
    float s = accum[(size_t)row * 129 + 128];
    out[i] = accum[(size_t)row * 129 + d] / s;
  } else {
    int n = i - EMB_ELEMS;
    out[EMB_ELEMS + n] = (float)(unsigned)(kExact[n] & 0x1FFFu);
  }
}

extern "C" void kernel_launch(void* const* d_in, const int* in_sizes, int n_in,
                              void* d_out, int out_size, void* d_ws, size_t ws_size,
                              hipStream_t stream) {
  const float* x = (const float*)d_in[0];
  const float* cb = (const float*)d_in[1];
  float* out = (float*)d_out;

  char* ws = (char*)d_ws;
  size_t off = 0;
  float* accum = (float*)(ws + off); off += (size_t)NROWS * 129 * 4;
  float* c2 = (float*)(ws + off); off += (size_t)VOCAB * 4;
  unsigned short* cbf = (unsigned short*)(ws + off); off += (size_t)VOCAB * DIM * 2;
  unsigned long long* kExact = (unsigned long long*)(ws + off); off += (size_t)NROWS * 8;
  unsigned int* cnt = (unsigned int*)(ws + off); off += 64;
  unsigned int* list = (unsigned int*)(ws + off);
  size_t cap32 = (ws_size > off) ? (ws_size - off) / 4 : 0;
  unsigned cap = (unsigned)(cap32 > LIST_CAP_MAX ? LIST_CAP_MAX : cap32);

  hipMemsetAsync(accum, 0, (size_t)NROWS * 129 * 4, stream);
  hipMemsetAsync(kExact, 0xFF, (size_t)NROWS * 8, stream);
  hipMemsetAsync(cnt, 0, 64, stream);

  k_prep<<<VOCAB / 16, 256, 0, stream>>>(cb, c2, cbf);
  k_main<<<dim3(NROWS / BN, VSPLITS), 256, 0, stream>>>(x, c2, cbf, accum, cnt, list, cap);
  k_fix<<<1024, 256, 0, stream>>>(x, cb, list, cnt, cap, kExact);
  k_rescue<<<NROWS / 4, 256, 0, stream>>>(x, cb, cnt, cap, kExact);
  k_out<<<(EMB_ELEMS + NROWS) / 256, 256, 0, stream>>>(accum, kExact, out);
}